// Round 9
// baseline (170.660 us; speedup 1.0000x reference)
//
#include <hip/hip_runtime.h>

// GCN 2-layer for MI355X (gfx950). fp32 GEMM, bf16 intermediates, fp32 out.
// out[v] = relu( dinv[v]*( g[v] + sum_{u->v} g[u] ) + b ),  g = dinv .* (x @ W)
//
// R8 -> R9 (one change): aggregate128 and gemm<64> fused. The wave's reduced
// h2 row goes LDS -> per-block 4x64 GEMM tile -> g2 (bf16), skipping the
// 51MB h2 HBM round-trip and one launch. CSR build path untouched (R7/R8-proven).
// Quarantined: R6's in-kernel shfl-scan rowstart fusion (replay nondeterminism).
// R3 lesson: zero global atomics. R5 lesson: gather-form aggregation only.

#define NPB 64    // nodes per bucket (power of 2)
#define PB  128   // partition chunk-blocks

typedef unsigned short ushort_t;
typedef unsigned int uint_t;

__device__ inline float bf2f_lo(uint_t u) { return __uint_as_float(u << 16); }
__device__ inline float bf2f_hi(uint_t u) { return __uint_as_float(u & 0xffff0000u); }
__device__ inline ushort_t f2bf(float f) {   // round-to-nearest-even
    uint_t x = __float_as_uint(f);
    uint_t r = x + 0x7fffu + ((x >> 16) & 1u);
    return (ushort_t)(r >> 16);
}

// ---------- scan machinery ----------

__global__ __launch_bounds__(256) void block_sum_kernel(const int* __restrict__ a, int L,
                                                        int* __restrict__ bsum) {
    __shared__ int red[256];
    int t = threadIdx.x;
    int base = blockIdx.x * 1024 + t * 4;
    int s = 0;
    if (base + 3 < L) {
        int4 v = *(const int4*)&a[base];
        s = v.x + v.y + v.z + v.w;
    } else {
        for (int i = 0; i < 4; ++i) if (base + i < L) s += a[base + i];
    }
    red[t] = s;
    __syncthreads();
    for (int off = 128; off > 0; off >>= 1) {
        if (t < off) red[t] += red[t + off];
        __syncthreads();
    }
    if (t == 0) bsum[blockIdx.x] = red[0];
}

// Merged: each block redundantly inclusive-scans bsum[0..nb-1] (nb<=256) in LDS,
// then does its local exclusive scan. In-place variant for the flat histogram.
__global__ __launch_bounds__(256) void local_scan_apply_kernel(int* __restrict__ arr, int L,
                                                               const int* __restrict__ bsum,
                                                               int nb) {
    __shared__ int sh[256];
    __shared__ int tsum[256];
    int b = blockIdx.x, t = threadIdx.x;
    sh[t] = (t < nb) ? bsum[t] : 0;
    __syncthreads();
    #pragma unroll
    for (int off = 1; off < 256; off <<= 1) {
        int w = (t >= off) ? sh[t - off] : 0;
        __syncthreads();
        sh[t] += w;
        __syncthreads();
    }
    int bprev = (b == 0) ? 0 : sh[b - 1];

    int base = b * 1024 + t * 4;
    int v[4];
    int s = 0;
    #pragma unroll
    for (int i = 0; i < 4; ++i) {
        int idx = base + i;
        v[i] = (idx < L) ? arr[idx] : 0;
        s += v[i];
    }
    tsum[t] = s;
    __syncthreads();
    for (int off = 1; off < 256; off <<= 1) {
        int w = (t >= off) ? tsum[t - off] : 0;
        __syncthreads();
        tsum[t] += w;
        __syncthreads();
    }
    int excl = (t == 0 ? 0 : tsum[t - 1]) + bprev;
    #pragma unroll
    for (int i = 0; i < 4; ++i) {
        int idx = base + i;
        if (idx < L) {
            arr[idx] = excl;
            excl += v[i];
        }
    }
}

// Merged node variant: cnt -> rowstart + dinv; also writes rowstart[n] = e.
__global__ __launch_bounds__(256) void local_scan_node_kernel(const int* __restrict__ cnt, int n,
                                                              const int* __restrict__ bsum,
                                                              int nb, int e_total,
                                                              int* __restrict__ rowstart,
                                                              float* __restrict__ dinv) {
    __shared__ int sh[256];
    __shared__ int tsum[256];
    int b = blockIdx.x, t = threadIdx.x;
    sh[t] = (t < nb) ? bsum[t] : 0;
    __syncthreads();
    #pragma unroll
    for (int off = 1; off < 256; off <<= 1) {
        int w = (t >= off) ? sh[t - off] : 0;
        __syncthreads();
        sh[t] += w;
        __syncthreads();
    }
    int bprev = (b == 0) ? 0 : sh[b - 1];

    int base = b * 1024 + t * 4;
    int v[4];
    int s = 0;
    #pragma unroll
    for (int i = 0; i < 4; ++i) {
        int idx = base + i;
        v[i] = (idx < n) ? cnt[idx] : 0;
        s += v[i];
    }
    tsum[t] = s;
    __syncthreads();
    for (int off = 1; off < 256; off <<= 1) {
        int w = (t >= off) ? tsum[t - off] : 0;
        __syncthreads();
        tsum[t] += w;
        __syncthreads();
    }
    int excl = (t == 0 ? 0 : tsum[t - 1]) + bprev;
    #pragma unroll
    for (int i = 0; i < 4; ++i) {
        int idx = base + i;
        if (idx < n) {
            rowstart[idx] = excl;
            excl += v[i];
            dinv[idx] = rsqrtf((float)(v[i] + 1));   // +1 self loop
        }
    }
    if (b == 0 && t == 0) rowstart[n] = e_total;
}

// ---------- radix partition (no global atomics) ----------

__global__ __launch_bounds__(256) void bucket_hist_kernel(const int* __restrict__ dst, int e,
                                                          int epb, int K,
                                                          int* __restrict__ hist) {
    __shared__ int lh[1024];
    int t = threadIdx.x, b = blockIdx.x;
    for (int k = t; k < K; k += 256) lh[k] = 0;
    __syncthreads();
    int lo = b * epb, hi = min(lo + epb, e);
    for (int i = lo + t; i < hi; i += 256) atomicAdd(&lh[dst[i] >> 6], 1);
    __syncthreads();
    for (int k = t; k < K; k += 256) hist[k * PB + b] = lh[k];
}

// scatter packed (src | dlocal<<16) into bucket regions (requires n <= 65536)
__global__ __launch_bounds__(256) void partition_kernel(const int* __restrict__ src,
                                                        const int* __restrict__ dst, int e,
                                                        int epb, int K,
                                                        const int* __restrict__ hist,
                                                        uint_t* __restrict__ ebuf) {
    __shared__ int loff[1024];
    int t = threadIdx.x, b = blockIdx.x;
    for (int k = t; k < K; k += 256) loff[k] = hist[k * PB + b];
    __syncthreads();
    int lo = b * epb, hi = min(lo + epb, e);
    for (int i = lo + t; i < hi; i += 256) {
        int d = dst[i];
        int k = d >> 6;
        int pos = atomicAdd(&loff[k], 1);   // LDS atomic only
        ebuf[pos] = (uint_t)src[i] | ((uint_t)(d & (NPB - 1)) << 16);
    }
}

// per-bucket node counts
__global__ __launch_bounds__(256) void bucket_count_kernel(const uint_t* __restrict__ ebuf,
                                                           const int* __restrict__ hist,
                                                           int e, int K, int n,
                                                           int* __restrict__ cnt) {
    __shared__ int c64[NPB];
    int t = threadIdx.x, k = blockIdx.x;
    if (t < NPB) c64[t] = 0;
    __syncthreads();
    int lo = hist[k * PB];
    int hi = (k + 1 < K) ? hist[(k + 1) * PB] : e;
    for (int i = lo + t; i < hi; i += 256) atomicAdd(&c64[(ebuf[i] >> 16) & (NPB - 1)], 1);
    __syncthreads();
    int node = k * NPB + t;
    if (t < NPB && node < n) cnt[node] = c64[t];
}

// per-bucket CSR fill: writes land in the bucket's ~4KB csr window
__global__ __launch_bounds__(256) void bucket_fill_kernel(const uint_t* __restrict__ ebuf,
                                                          const int* __restrict__ hist,
                                                          const int* __restrict__ rowstart,
                                                          int e, int K, int n,
                                                          int* __restrict__ csr_src) {
    __shared__ int rs[NPB];
    __shared__ int c64[NPB];
    int t = threadIdx.x, k = blockIdx.x;
    if (t < NPB) {
        int node = k * NPB + t;
        rs[t] = (node < n) ? rowstart[node] : 0;
        c64[t] = 0;
    }
    __syncthreads();
    int lo = hist[k * PB];
    int hi = (k + 1 < K) ? hist[(k + 1) * PB] : e;
    for (int i = lo + t; i < hi; i += 256) {
        uint_t u = ebuf[i];
        int dl = (u >> 16) & (NPB - 1);
        int slot = rs[dl] + atomicAdd(&c64[dl], 1);   // LDS atomic only
        csr_src[slot] = (int)(u & 0xffffu);
    }
}

// ---------- GEMM: C_bf16[n,COLS] = dinv[row] * (A[n,128] @ W[128,COLS]) ----------
#define K_DIM 128
template <int COLS>
__global__ __launch_bounds__(256) void gemm_scale_kernel(const float* __restrict__ A,
                                                         const float* __restrict__ W,
                                                         const float* __restrict__ dinv,
                                                         ushort_t* __restrict__ out, int n) {
    constexpr int CG  = COLS / 4;
    constexpr int RG  = 256 / CG;
    constexpr int RPT = 64 / RG;
    __shared__ float Asl[64][132];   // 132*4B row stride: 16B aligned
    int t    = threadIdx.x;
    int row0 = blockIdx.x * 64;

    #pragma unroll
    for (int it = 0; it < 8; ++it) {
        int idx = (it * 256 + t) * 4;
        int r = idx >> 7;
        int k = idx & 127;
        int gr = row0 + r;
        float4 v = {0.f, 0.f, 0.f, 0.f};
        if (gr < n) v = *(const float4*)&A[gr * K_DIM + k];
        *(float4*)&Asl[r][k] = v;
    }
    __syncthreads();

    int cg = t % CG, rg = t / CG;
    int c0 = cg * 4;
    float acc[RPT][4];
    #pragma unroll
    for (int i = 0; i < RPT; ++i)
        for (int j = 0; j < 4; ++j) acc[i][j] = 0.f;

    const float4* W4 = (const float4*)W;
    constexpr int WS = COLS / 4;   // float4 per W row

    for (int k0 = 0; k0 < K_DIM; k0 += 4) {
        float4 w0 = W4[(k0 + 0) * WS + cg];
        float4 w1 = W4[(k0 + 1) * WS + cg];
        float4 w2 = W4[(k0 + 2) * WS + cg];
        float4 w3 = W4[(k0 + 3) * WS + cg];
        #pragma unroll
        for (int i = 0; i < RPT; ++i) {
            float4 a = *(const float4*)&Asl[rg * RPT + i][k0];
            acc[i][0] = fmaf(a.x, w0.x, acc[i][0]);
            acc[i][1] = fmaf(a.x, w0.y, acc[i][1]);
            acc[i][2] = fmaf(a.x, w0.z, acc[i][2]);
            acc[i][3] = fmaf(a.x, w0.w, acc[i][3]);
            acc[i][0] = fmaf(a.y, w1.x, acc[i][0]);
            acc[i][1] = fmaf(a.y, w1.y, acc[i][1]);
            acc[i][2] = fmaf(a.y, w1.z, acc[i][2]);
            acc[i][3] = fmaf(a.y, w1.w, acc[i][3]);
            acc[i][0] = fmaf(a.z, w2.x, acc[i][0]);
            acc[i][1] = fmaf(a.z, w2.y, acc[i][1]);
            acc[i][2] = fmaf(a.z, w2.z, acc[i][2]);
            acc[i][3] = fmaf(a.z, w2.w, acc[i][3]);
            acc[i][0] = fmaf(a.w, w3.x, acc[i][0]);
            acc[i][1] = fmaf(a.w, w3.y, acc[i][1]);
            acc[i][2] = fmaf(a.w, w3.z, acc[i][2]);
            acc[i][3] = fmaf(a.w, w3.w, acc[i][3]);
        }
    }

    #pragma unroll
    for (int i = 0; i < RPT; ++i) {
        int r = row0 + rg * RPT + i;
        if (r < n) {
            float s = dinv[r];
            ushort4 o;
            o.x = f2bf(acc[i][0] * s);
            o.y = f2bf(acc[i][1] * s);
            o.z = f2bf(acc[i][2] * s);
            o.w = f2bf(acc[i][3] * s);
            *(ushort4*)&out[r * COLS + c0] = o;
        }
    }
}

// ---------- FUSED: aggregate128 (gather h2 row) + 4x64 GEMM tile -> g2 bf16 ----------
// Phase 1 (per wave, = proven aggregate128): h2row = relu(dinv*(self+sum)+b1) -> LDS.
// Phase 2 (whole block): g2[v][c] = f2bf( dinv[v] * sum_k h2row[nd][k]*W2[k*64+c] ).
// h2 never touches HBM (saves 51MB round-trip + one launch).
__global__ __launch_bounds__(256) void fused_agg128_gemm64_kernel(
        const ushort_t* __restrict__ g,
        const int* __restrict__ rowstart,
        const int* __restrict__ csr_src,
        const float* __restrict__ dinv,
        const float* __restrict__ bias,
        const float* __restrict__ W2,
        ushort_t* __restrict__ g2, int n) {
    __shared__ float hrow[4][128];   // 2KB; phase-2 reads are wave-broadcast
    int wave = threadIdx.x >> 6;
    int lane = threadIdx.x & 63;
    int v = blockIdx.x * 4 + wave;

    // ---- phase 1: gather + reduce (no early returns: barrier below) ----
    if (v < n) {
        int s    = __builtin_amdgcn_readfirstlane(rowstart[v]);
        int epos = __builtin_amdgcn_readfirstlane(rowstart[v + 1]);
        int eg = lane >> 4;        // edge sub-lane 0..3
        int f  = lane & 15;        // feature group (8 feats = 16B)

        float a0 = 0.f, a1 = 0.f, a2 = 0.f, a3 = 0.f, a4 = 0.f, a5 = 0.f, a6 = 0.f, a7 = 0.f;
        if (lane < 16) {   // self row
            uint4 m = *(const uint4*)&g[(size_t)v * 128 + f * 8];
            a0 = bf2f_lo(m.x); a1 = bf2f_hi(m.x);
            a2 = bf2f_lo(m.y); a3 = bf2f_hi(m.y);
            a4 = bf2f_lo(m.z); a5 = bf2f_hi(m.z);
            a6 = bf2f_lo(m.w); a7 = bf2f_hi(m.w);
        }

        #pragma unroll 2
        for (int j = s; j < epos; j += 4) {
            int idx = j + eg;
            int safe = min(idx, epos - 1);
            int u = csr_src[safe];
            float w = (idx < epos) ? 1.f : 0.f;
            uint4 m = *(const uint4*)&g[(size_t)u * 128 + f * 8];
            a0 = fmaf(w, bf2f_lo(m.x), a0); a1 = fmaf(w, bf2f_hi(m.x), a1);
            a2 = fmaf(w, bf2f_lo(m.y), a2); a3 = fmaf(w, bf2f_hi(m.y), a3);
            a4 = fmaf(w, bf2f_lo(m.z), a4); a5 = fmaf(w, bf2f_hi(m.z), a5);
            a6 = fmaf(w, bf2f_lo(m.w), a6); a7 = fmaf(w, bf2f_hi(m.w), a7);
        }

        a0 += __shfl_xor(a0, 16); a1 += __shfl_xor(a1, 16);
        a2 += __shfl_xor(a2, 16); a3 += __shfl_xor(a3, 16);
        a4 += __shfl_xor(a4, 16); a5 += __shfl_xor(a5, 16);
        a6 += __shfl_xor(a6, 16); a7 += __shfl_xor(a7, 16);
        a0 += __shfl_xor(a0, 32); a1 += __shfl_xor(a1, 32);
        a2 += __shfl_xor(a2, 32); a3 += __shfl_xor(a3, 32);
        a4 += __shfl_xor(a4, 32); a5 += __shfl_xor(a5, 32);
        a6 += __shfl_xor(a6, 32); a7 += __shfl_xor(a7, 32);

        if (lane < 16) {
            int f8 = (lane & 15) * 8;
            float dv = dinv[v];
            float4 b0 = *(const float4*)&bias[f8];
            float4 b1v = *(const float4*)&bias[f8 + 4];
            float4 o0 = {fmaxf(fmaf(a0, dv, b0.x), 0.f), fmaxf(fmaf(a1, dv, b0.y), 0.f),
                         fmaxf(fmaf(a2, dv, b0.z), 0.f), fmaxf(fmaf(a3, dv, b0.w), 0.f)};
            float4 o1 = {fmaxf(fmaf(a4, dv, b1v.x), 0.f), fmaxf(fmaf(a5, dv, b1v.y), 0.f),
                         fmaxf(fmaf(a6, dv, b1v.z), 0.f), fmaxf(fmaf(a7, dv, b1v.w), 0.f)};
            *(float4*)&hrow[wave][f8] = o0;
            *(float4*)&hrow[wave][f8 + 4] = o1;
        }
    }
    __syncthreads();

    // ---- phase 2: thread (nd,c) computes one g2 element ----
    int nd = threadIdx.x >> 6;     // node within block (=wave id)
    int c  = threadIdx.x & 63;     // output column
    int vv = blockIdx.x * 4 + nd;
    if (vv < n) {
        const float4* h4 = (const float4*)&hrow[nd][0];
        float acc0 = 0.f, acc1 = 0.f, acc2 = 0.f, acc3 = 0.f;
        #pragma unroll
        for (int k4 = 0; k4 < 32; ++k4) {
            float4 h = h4[k4];   // ds_read_b128, broadcast across the wave
            acc0 = fmaf(h.x, W2[(k4 * 4 + 0) * 64 + c], acc0);
            acc1 = fmaf(h.y, W2[(k4 * 4 + 1) * 64 + c], acc1);
            acc2 = fmaf(h.z, W2[(k4 * 4 + 2) * 64 + c], acc2);
            acc3 = fmaf(h.w, W2[(k4 * 4 + 3) * 64 + c], acc3);
        }
        float acc = (acc0 + acc1) + (acc2 + acc3);
        g2[(size_t)vv * 64 + c] = f2bf(acc * dinv[vv]);
    }
}

// ---------- aggregation 64-col (final layer): wave = 8 edge-lanes x 8 feat-lanes ----------

__global__ __launch_bounds__(256) void aggregate64_kernel(const ushort_t* __restrict__ g,
                                                          const int* __restrict__ rowstart,
                                                          const int* __restrict__ csr_src,
                                                          const float* __restrict__ dinv,
                                                          const float* __restrict__ bias,
                                                          float* __restrict__ out, int n) {
    int wave = threadIdx.x >> 6;
    int lane = threadIdx.x & 63;
    int v = blockIdx.x * 4 + wave;
    if (v >= n) return;
    int s    = __builtin_amdgcn_readfirstlane(rowstart[v]);
    int epos = __builtin_amdgcn_readfirstlane(rowstart[v + 1]);
    int eg = lane >> 3;        // edge sub-lane 0..7
    int f  = lane & 7;         // feats f*8..f*8+7

    float a0 = 0.f, a1 = 0.f, a2 = 0.f, a3 = 0.f, a4 = 0.f, a5 = 0.f, a6 = 0.f, a7 = 0.f;
    if (lane < 8) {   // self row
        uint4 m = *(const uint4*)&g[(size_t)v * 64 + f * 8];
        a0 = bf2f_lo(m.x); a1 = bf2f_hi(m.x);
        a2 = bf2f_lo(m.y); a3 = bf2f_hi(m.y);
        a4 = bf2f_lo(m.z); a5 = bf2f_hi(m.z);
        a6 = bf2f_lo(m.w); a7 = bf2f_hi(m.w);
    }

    #pragma unroll 2
    for (int j = s; j < epos; j += 8) {
        int idx = j + eg;
        int safe = min(idx, epos - 1);
        int u = csr_src[safe];
        float w = (idx < epos) ? 1.f : 0.f;
        uint4 m = *(const uint4*)&g[(size_t)u * 64 + f * 8];
        a0 = fmaf(w, bf2f_lo(m.x), a0); a1 = fmaf(w, bf2f_hi(m.x), a1);
        a2 = fmaf(w, bf2f_lo(m.y), a2); a3 = fmaf(w, bf2f_hi(m.y), a3);
        a4 = fmaf(w, bf2f_lo(m.z), a4); a5 = fmaf(w, bf2f_hi(m.z), a5);
        a6 = fmaf(w, bf2f_lo(m.w), a6); a7 = fmaf(w, bf2f_hi(m.w), a7);
    }

    a0 += __shfl_xor(a0, 8);  a1 += __shfl_xor(a1, 8);
    a2 += __shfl_xor(a2, 8);  a3 += __shfl_xor(a3, 8);
    a4 += __shfl_xor(a4, 8);  a5 += __shfl_xor(a5, 8);
    a6 += __shfl_xor(a6, 8);  a7 += __shfl_xor(a7, 8);
    a0 += __shfl_xor(a0, 16); a1 += __shfl_xor(a1, 16);
    a2 += __shfl_xor(a2, 16); a3 += __shfl_xor(a3, 16);
    a4 += __shfl_xor(a4, 16); a5 += __shfl_xor(a5, 16);
    a6 += __shfl_xor(a6, 16); a7 += __shfl_xor(a7, 16);
    a0 += __shfl_xor(a0, 32); a1 += __shfl_xor(a1, 32);
    a2 += __shfl_xor(a2, 32); a3 += __shfl_xor(a3, 32);
    a4 += __shfl_xor(a4, 32); a5 += __shfl_xor(a5, 32);
    a6 += __shfl_xor(a6, 32); a7 += __shfl_xor(a7, 32);

    if (lane < 8) {
        float dv = dinv[v];
        float4 b0 = *(const float4*)&bias[f * 8];
        float4 b1 = *(const float4*)&bias[f * 8 + 4];
        float4 o0 = {fmaxf(fmaf(a0, dv, b0.x), 0.f), fmaxf(fmaf(a1, dv, b0.y), 0.f),
                     fmaxf(fmaf(a2, dv, b0.z), 0.f), fmaxf(fmaf(a3, dv, b0.w), 0.f)};
        float4 o1 = {fmaxf(fmaf(a4, dv, b1.x), 0.f), fmaxf(fmaf(a5, dv, b1.y), 0.f),
                     fmaxf(fmaf(a6, dv, b1.z), 0.f), fmaxf(fmaf(a7, dv, b1.w), 0.f)};
        *(float4*)&out[(size_t)v * 64 + f * 8] = o0;
        *(float4*)&out[(size_t)v * 64 + f * 8 + 4] = o1;
    }
}

extern "C" void kernel_launch(void* const* d_in, const int* in_sizes, int n_in,
                              void* d_out, int out_size, void* d_ws, size_t ws_size,
                              hipStream_t stream) {
    const float* x  = (const float*)d_in[0];
    const int*   ei = (const int*)d_in[1];   // [2, E] int32
    const float* W1 = (const float*)d_in[2];
    const float* b1 = (const float*)d_in[3];
    const float* W2 = (const float*)d_in[4];
    const float* b2 = (const float*)d_in[5];
    float* out = (float*)d_out;

    const int n = in_sizes[0] / 128;   // 50000 (<= 65536 required for packing)
    const int e = in_sizes[1] / 2;     // 800000
    const int* src = ei;
    const int* dst = ei + e;
    const int K   = (n + NPB - 1) / NPB;       // 782 buckets
    const int epb = (e + PB - 1) / PB;         // edges per chunk-block
    const int L   = K * PB;                    // flat histogram length

    char* ws = (char*)d_ws;
    size_t off = 0;
    auto carve = [&](size_t bytes) -> void* {
        void* p = ws + off;
        off = (off + bytes + 255) & ~(size_t)255;
        return p;
    };
    int*      hist     = (int*)     carve((size_t)L * 4);
    int*      bsum     = (int*)     carve((size_t)1024 * 4);
    int*      cnt      = (int*)     carve((size_t)n * 4);
    int*      rowstart = (int*)     carve((size_t)(n + 1) * 4);
    float*    dinv     = (float*)   carve((size_t)n * 4);
    uint_t*   ebuf     = (uint_t*)  carve((size_t)e * 4);
    int*      csr_src  = (int*)     carve((size_t)e * 4);
    ushort_t* g1       = (ushort_t*)carve((size_t)n * 128 * 2);
    ushort_t* g2       = (ushort_t*)carve((size_t)n * 64 * 2);
    (void)ws_size;

    const int nbL = (L + 1023) / 1024;   // hist scan blocks (<=256 required)
    const int nbN = (n + 1023) / 1024;   // node scan blocks (<=256 required)

    // --- CSR build, zero global atomics, zero memsets, 8 launches ---
    bucket_hist_kernel<<<PB, 256, 0, stream>>>(dst, e, epb, K, hist);
    block_sum_kernel<<<nbL, 256, 0, stream>>>(hist, L, bsum);
    local_scan_apply_kernel<<<nbL, 256, 0, stream>>>(hist, L, bsum, nbL);
    partition_kernel<<<PB, 256, 0, stream>>>(src, dst, e, epb, K, hist, ebuf);
    bucket_count_kernel<<<K, 256, 0, stream>>>(ebuf, hist, e, K, n, cnt);
    block_sum_kernel<<<nbN, 256, 0, stream>>>(cnt, n, bsum);
    local_scan_node_kernel<<<nbN, 256, 0, stream>>>(cnt, n, bsum, nbN, e, rowstart, dinv);
    bucket_fill_kernel<<<K, 256, 0, stream>>>(ebuf, hist, rowstart, e, K, n, csr_src);

    // --- layers (h2 fused away) ---
    const int gblocks = (n + 63) / 64;
    const int ablocks = (n + 3) / 4;
    gemm_scale_kernel<128><<<gblocks, 256, 0, stream>>>(x, W1, dinv, g1, n);
    fused_agg128_gemm64_kernel<<<ablocks, 256, 0, stream>>>(g1, rowstart, csr_src, dinv,
                                                            b1, W2, g2, n);
    aggregate64_kernel<<<ablocks, 256, 0, stream>>>(g2, rowstart, csr_src, dinv, b2, out, n);
}

// Round 10
// 158.343 us; speedup vs baseline: 1.0778x; 1.0778x over previous
//
#include <hip/hip_runtime.h>

// GCN 2-layer for MI355X (gfx950). fp32 GEMM, bf16 intermediates, fp32 out.
// out[v] = relu( dinv[v]*( g[v] + sum_{u->v} g[u] ) + b ),  g = dinv .* (x @ W)
//
// R9 -> R10: fusion REVERTED (R9: +12us; phase-2 re-read W2 16x, and showed
// gather runs at 1.1 TB/s = request-bound, not BW-bound). One change vs R8:
// aggregate128 remapped to 8 edge-lanes x 8 feat-lanes x 32B/lane -> 8 rows
// in flight per iteration (2x R8), attacking the measured parallelism limit.
// Quarantined: R6 fused rowstart scan (replay nondeterminism); R9 fusion.
// R3 lesson: zero global atomics. R5 lesson: gather-form aggregation only.

#define NPB 64    // nodes per bucket (power of 2)
#define PB  128   // partition chunk-blocks

typedef unsigned short ushort_t;
typedef unsigned int uint_t;

__device__ inline float bf2f_lo(uint_t u) { return __uint_as_float(u << 16); }
__device__ inline float bf2f_hi(uint_t u) { return __uint_as_float(u & 0xffff0000u); }
__device__ inline ushort_t f2bf(float f) {   // round-to-nearest-even
    uint_t x = __float_as_uint(f);
    uint_t r = x + 0x7fffu + ((x >> 16) & 1u);
    return (ushort_t)(r >> 16);
}

// ---------- scan machinery ----------

__global__ __launch_bounds__(256) void block_sum_kernel(const int* __restrict__ a, int L,
                                                        int* __restrict__ bsum) {
    __shared__ int red[256];
    int t = threadIdx.x;
    int base = blockIdx.x * 1024 + t * 4;
    int s = 0;
    if (base + 3 < L) {
        int4 v = *(const int4*)&a[base];
        s = v.x + v.y + v.z + v.w;
    } else {
        for (int i = 0; i < 4; ++i) if (base + i < L) s += a[base + i];
    }
    red[t] = s;
    __syncthreads();
    for (int off = 128; off > 0; off >>= 1) {
        if (t < off) red[t] += red[t + off];
        __syncthreads();
    }
    if (t == 0) bsum[blockIdx.x] = red[0];
}

// Merged: each block redundantly inclusive-scans bsum[0..nb-1] (nb<=256) in LDS,
// then does its local exclusive scan. In-place variant for the flat histogram.
__global__ __launch_bounds__(256) void local_scan_apply_kernel(int* __restrict__ arr, int L,
                                                               const int* __restrict__ bsum,
                                                               int nb) {
    __shared__ int sh[256];
    __shared__ int tsum[256];
    int b = blockIdx.x, t = threadIdx.x;
    sh[t] = (t < nb) ? bsum[t] : 0;
    __syncthreads();
    #pragma unroll
    for (int off = 1; off < 256; off <<= 1) {
        int w = (t >= off) ? sh[t - off] : 0;
        __syncthreads();
        sh[t] += w;
        __syncthreads();
    }
    int bprev = (b == 0) ? 0 : sh[b - 1];

    int base = b * 1024 + t * 4;
    int v[4];
    int s = 0;
    #pragma unroll
    for (int i = 0; i < 4; ++i) {
        int idx = base + i;
        v[i] = (idx < L) ? arr[idx] : 0;
        s += v[i];
    }
    tsum[t] = s;
    __syncthreads();
    for (int off = 1; off < 256; off <<= 1) {
        int w = (t >= off) ? tsum[t - off] : 0;
        __syncthreads();
        tsum[t] += w;
        __syncthreads();
    }
    int excl = (t == 0 ? 0 : tsum[t - 1]) + bprev;
    #pragma unroll
    for (int i = 0; i < 4; ++i) {
        int idx = base + i;
        if (idx < L) {
            arr[idx] = excl;
            excl += v[i];
        }
    }
}

// Merged node variant: cnt -> rowstart + dinv; also writes rowstart[n] = e.
__global__ __launch_bounds__(256) void local_scan_node_kernel(const int* __restrict__ cnt, int n,
                                                              const int* __restrict__ bsum,
                                                              int nb, int e_total,
                                                              int* __restrict__ rowstart,
                                                              float* __restrict__ dinv) {
    __shared__ int sh[256];
    __shared__ int tsum[256];
    int b = blockIdx.x, t = threadIdx.x;
    sh[t] = (t < nb) ? bsum[t] : 0;
    __syncthreads();
    #pragma unroll
    for (int off = 1; off < 256; off <<= 1) {
        int w = (t >= off) ? sh[t - off] : 0;
        __syncthreads();
        sh[t] += w;
        __syncthreads();
    }
    int bprev = (b == 0) ? 0 : sh[b - 1];

    int base = b * 1024 + t * 4;
    int v[4];
    int s = 0;
    #pragma unroll
    for (int i = 0; i < 4; ++i) {
        int idx = base + i;
        v[i] = (idx < n) ? cnt[idx] : 0;
        s += v[i];
    }
    tsum[t] = s;
    __syncthreads();
    for (int off = 1; off < 256; off <<= 1) {
        int w = (t >= off) ? tsum[t - off] : 0;
        __syncthreads();
        tsum[t] += w;
        __syncthreads();
    }
    int excl = (t == 0 ? 0 : tsum[t - 1]) + bprev;
    #pragma unroll
    for (int i = 0; i < 4; ++i) {
        int idx = base + i;
        if (idx < n) {
            rowstart[idx] = excl;
            excl += v[i];
            dinv[idx] = rsqrtf((float)(v[i] + 1));   // +1 self loop
        }
    }
    if (b == 0 && t == 0) rowstart[n] = e_total;
}

// ---------- radix partition (no global atomics) ----------

__global__ __launch_bounds__(256) void bucket_hist_kernel(const int* __restrict__ dst, int e,
                                                          int epb, int K,
                                                          int* __restrict__ hist) {
    __shared__ int lh[1024];
    int t = threadIdx.x, b = blockIdx.x;
    for (int k = t; k < K; k += 256) lh[k] = 0;
    __syncthreads();
    int lo = b * epb, hi = min(lo + epb, e);
    for (int i = lo + t; i < hi; i += 256) atomicAdd(&lh[dst[i] >> 6], 1);
    __syncthreads();
    for (int k = t; k < K; k += 256) hist[k * PB + b] = lh[k];
}

// scatter packed (src | dlocal<<16) into bucket regions (requires n <= 65536)
__global__ __launch_bounds__(256) void partition_kernel(const int* __restrict__ src,
                                                        const int* __restrict__ dst, int e,
                                                        int epb, int K,
                                                        const int* __restrict__ hist,
                                                        uint_t* __restrict__ ebuf) {
    __shared__ int loff[1024];
    int t = threadIdx.x, b = blockIdx.x;
    for (int k = t; k < K; k += 256) loff[k] = hist[k * PB + b];
    __syncthreads();
    int lo = b * epb, hi = min(lo + epb, e);
    for (int i = lo + t; i < hi; i += 256) {
        int d = dst[i];
        int k = d >> 6;
        int pos = atomicAdd(&loff[k], 1);   // LDS atomic only
        ebuf[pos] = (uint_t)src[i] | ((uint_t)(d & (NPB - 1)) << 16);
    }
}

// per-bucket node counts
__global__ __launch_bounds__(256) void bucket_count_kernel(const uint_t* __restrict__ ebuf,
                                                           const int* __restrict__ hist,
                                                           int e, int K, int n,
                                                           int* __restrict__ cnt) {
    __shared__ int c64[NPB];
    int t = threadIdx.x, k = blockIdx.x;
    if (t < NPB) c64[t] = 0;
    __syncthreads();
    int lo = hist[k * PB];
    int hi = (k + 1 < K) ? hist[(k + 1) * PB] : e;
    for (int i = lo + t; i < hi; i += 256) atomicAdd(&c64[(ebuf[i] >> 16) & (NPB - 1)], 1);
    __syncthreads();
    int node = k * NPB + t;
    if (t < NPB && node < n) cnt[node] = c64[t];
}

// per-bucket CSR fill: writes land in the bucket's ~4KB csr window
__global__ __launch_bounds__(256) void bucket_fill_kernel(const uint_t* __restrict__ ebuf,
                                                          const int* __restrict__ hist,
                                                          const int* __restrict__ rowstart,
                                                          int e, int K, int n,
                                                          int* __restrict__ csr_src) {
    __shared__ int rs[NPB];
    __shared__ int c64[NPB];
    int t = threadIdx.x, k = blockIdx.x;
    if (t < NPB) {
        int node = k * NPB + t;
        rs[t] = (node < n) ? rowstart[node] : 0;
        c64[t] = 0;
    }
    __syncthreads();
    int lo = hist[k * PB];
    int hi = (k + 1 < K) ? hist[(k + 1) * PB] : e;
    for (int i = lo + t; i < hi; i += 256) {
        uint_t u = ebuf[i];
        int dl = (u >> 16) & (NPB - 1);
        int slot = rs[dl] + atomicAdd(&c64[dl], 1);   // LDS atomic only
        csr_src[slot] = (int)(u & 0xffffu);
    }
}

// ---------- GEMM: C_bf16[n,COLS] = dinv[row] * (A[n,128] @ W[128,COLS]) ----------
#define K_DIM 128
template <int COLS>
__global__ __launch_bounds__(256) void gemm_scale_kernel(const float* __restrict__ A,
                                                         const float* __restrict__ W,
                                                         const float* __restrict__ dinv,
                                                         ushort_t* __restrict__ out, int n) {
    constexpr int CG  = COLS / 4;
    constexpr int RG  = 256 / CG;
    constexpr int RPT = 64 / RG;
    __shared__ float Asl[64][132];   // 132*4B row stride: 16B aligned
    int t    = threadIdx.x;
    int row0 = blockIdx.x * 64;

    #pragma unroll
    for (int it = 0; it < 8; ++it) {
        int idx = (it * 256 + t) * 4;
        int r = idx >> 7;
        int k = idx & 127;
        int gr = row0 + r;
        float4 v = {0.f, 0.f, 0.f, 0.f};
        if (gr < n) v = *(const float4*)&A[gr * K_DIM + k];
        *(float4*)&Asl[r][k] = v;
    }
    __syncthreads();

    int cg = t % CG, rg = t / CG;
    int c0 = cg * 4;
    float acc[RPT][4];
    #pragma unroll
    for (int i = 0; i < RPT; ++i)
        for (int j = 0; j < 4; ++j) acc[i][j] = 0.f;

    const float4* W4 = (const float4*)W;
    constexpr int WS = COLS / 4;   // float4 per W row

    for (int k0 = 0; k0 < K_DIM; k0 += 4) {
        float4 w0 = W4[(k0 + 0) * WS + cg];
        float4 w1 = W4[(k0 + 1) * WS + cg];
        float4 w2 = W4[(k0 + 2) * WS + cg];
        float4 w3 = W4[(k0 + 3) * WS + cg];
        #pragma unroll
        for (int i = 0; i < RPT; ++i) {
            float4 a = *(const float4*)&Asl[rg * RPT + i][k0];
            acc[i][0] = fmaf(a.x, w0.x, acc[i][0]);
            acc[i][1] = fmaf(a.x, w0.y, acc[i][1]);
            acc[i][2] = fmaf(a.x, w0.z, acc[i][2]);
            acc[i][3] = fmaf(a.x, w0.w, acc[i][3]);
            acc[i][0] = fmaf(a.y, w1.x, acc[i][0]);
            acc[i][1] = fmaf(a.y, w1.y, acc[i][1]);
            acc[i][2] = fmaf(a.y, w1.z, acc[i][2]);
            acc[i][3] = fmaf(a.y, w1.w, acc[i][3]);
            acc[i][0] = fmaf(a.z, w2.x, acc[i][0]);
            acc[i][1] = fmaf(a.z, w2.y, acc[i][1]);
            acc[i][2] = fmaf(a.z, w2.z, acc[i][2]);
            acc[i][3] = fmaf(a.z, w2.w, acc[i][3]);
            acc[i][0] = fmaf(a.w, w3.x, acc[i][0]);
            acc[i][1] = fmaf(a.w, w3.y, acc[i][1]);
            acc[i][2] = fmaf(a.w, w3.z, acc[i][2]);
            acc[i][3] = fmaf(a.w, w3.w, acc[i][3]);
        }
    }

    #pragma unroll
    for (int i = 0; i < RPT; ++i) {
        int r = row0 + rg * RPT + i;
        if (r < n) {
            float s = dinv[r];
            ushort4 o;
            o.x = f2bf(acc[i][0] * s);
            o.y = f2bf(acc[i][1] * s);
            o.z = f2bf(acc[i][2] * s);
            o.w = f2bf(acc[i][3] * s);
            *(ushort4*)&out[r * COLS + c0] = o;
        }
    }
}

// ---------- aggregation 128-col: wave = 8 edge-lanes x 8 feat-lanes, 32B/lane ----------
// 8 rows in flight per iteration (16 with unroll 2) — attacks the measured
// 1.1 TB/s request-bound gather (R9 profile).
__global__ __launch_bounds__(256) void aggregate128_kernel(const ushort_t* __restrict__ g,
                                                           const int* __restrict__ rowstart,
                                                           const int* __restrict__ csr_src,
                                                           const float* __restrict__ dinv,
                                                           const float* __restrict__ bias,
                                                           float* __restrict__ out, int n) {
    int wave = threadIdx.x >> 6;
    int lane = threadIdx.x & 63;
    int v = blockIdx.x * 4 + wave;
    if (v >= n) return;
    int s    = __builtin_amdgcn_readfirstlane(rowstart[v]);
    int epos = __builtin_amdgcn_readfirstlane(rowstart[v + 1]);
    int eg = lane >> 3;        // edge sub-lane 0..7
    int f  = lane & 7;         // feature group: feats f*16 .. f*16+15 (32B)

    float a0 = 0.f, a1 = 0.f, a2 = 0.f, a3 = 0.f, a4 = 0.f, a5 = 0.f, a6 = 0.f, a7 = 0.f;
    float a8 = 0.f, a9 = 0.f, aA = 0.f, aB = 0.f, aC = 0.f, aD = 0.f, aE = 0.f, aF = 0.f;
    if (lane < 8) {   // self row
        uint4 m0 = *(const uint4*)&g[(size_t)v * 128 + f * 16];
        uint4 m1 = *(const uint4*)&g[(size_t)v * 128 + f * 16 + 8];
        a0 = bf2f_lo(m0.x); a1 = bf2f_hi(m0.x);
        a2 = bf2f_lo(m0.y); a3 = bf2f_hi(m0.y);
        a4 = bf2f_lo(m0.z); a5 = bf2f_hi(m0.z);
        a6 = bf2f_lo(m0.w); a7 = bf2f_hi(m0.w);
        a8 = bf2f_lo(m1.x); a9 = bf2f_hi(m1.x);
        aA = bf2f_lo(m1.y); aB = bf2f_hi(m1.y);
        aC = bf2f_lo(m1.z); aD = bf2f_hi(m1.z);
        aE = bf2f_lo(m1.w); aF = bf2f_hi(m1.w);
    }

    #pragma unroll 2
    for (int j = s; j < epos; j += 8) {
        int idx = j + eg;
        int safe = min(idx, epos - 1);
        int u = csr_src[safe];
        float w = (idx < epos) ? 1.f : 0.f;
        uint4 m0 = *(const uint4*)&g[(size_t)u * 128 + f * 16];
        uint4 m1 = *(const uint4*)&g[(size_t)u * 128 + f * 16 + 8];
        a0 = fmaf(w, bf2f_lo(m0.x), a0); a1 = fmaf(w, bf2f_hi(m0.x), a1);
        a2 = fmaf(w, bf2f_lo(m0.y), a2); a3 = fmaf(w, bf2f_hi(m0.y), a3);
        a4 = fmaf(w, bf2f_lo(m0.z), a4); a5 = fmaf(w, bf2f_hi(m0.z), a5);
        a6 = fmaf(w, bf2f_lo(m0.w), a6); a7 = fmaf(w, bf2f_hi(m0.w), a7);
        a8 = fmaf(w, bf2f_lo(m1.x), a8); a9 = fmaf(w, bf2f_hi(m1.x), a9);
        aA = fmaf(w, bf2f_lo(m1.y), aA); aB = fmaf(w, bf2f_hi(m1.y), aB);
        aC = fmaf(w, bf2f_lo(m1.z), aC); aD = fmaf(w, bf2f_hi(m1.z), aD);
        aE = fmaf(w, bf2f_lo(m1.w), aE); aF = fmaf(w, bf2f_hi(m1.w), aF);
    }

    // combine 8 edge sub-lanes (xor over lane bits 3,4,5)
    #pragma unroll
    for (int m = 8; m <= 32; m <<= 1) {
        a0 += __shfl_xor(a0, m); a1 += __shfl_xor(a1, m);
        a2 += __shfl_xor(a2, m); a3 += __shfl_xor(a3, m);
        a4 += __shfl_xor(a4, m); a5 += __shfl_xor(a5, m);
        a6 += __shfl_xor(a6, m); a7 += __shfl_xor(a7, m);
        a8 += __shfl_xor(a8, m); a9 += __shfl_xor(a9, m);
        aA += __shfl_xor(aA, m); aB += __shfl_xor(aB, m);
        aC += __shfl_xor(aC, m); aD += __shfl_xor(aD, m);
        aE += __shfl_xor(aE, m); aF += __shfl_xor(aF, m);
    }

    if (lane < 8) {
        float dv = dinv[v];
        int c0 = f * 16;
        float4 b0 = *(const float4*)&bias[c0];
        float4 b1 = *(const float4*)&bias[c0 + 4];
        float4 b2 = *(const float4*)&bias[c0 + 8];
        float4 b3 = *(const float4*)&bias[c0 + 12];
        float4 o0 = {fmaxf(fmaf(a0, dv, b0.x), 0.f), fmaxf(fmaf(a1, dv, b0.y), 0.f),
                     fmaxf(fmaf(a2, dv, b0.z), 0.f), fmaxf(fmaf(a3, dv, b0.w), 0.f)};
        float4 o1 = {fmaxf(fmaf(a4, dv, b1.x), 0.f), fmaxf(fmaf(a5, dv, b1.y), 0.f),
                     fmaxf(fmaf(a6, dv, b1.z), 0.f), fmaxf(fmaf(a7, dv, b1.w), 0.f)};
        float4 o2 = {fmaxf(fmaf(a8, dv, b2.x), 0.f), fmaxf(fmaf(a9, dv, b2.y), 0.f),
                     fmaxf(fmaf(aA, dv, b2.z), 0.f), fmaxf(fmaf(aB, dv, b2.w), 0.f)};
        float4 o3 = {fmaxf(fmaf(aC, dv, b3.x), 0.f), fmaxf(fmaf(aD, dv, b3.y), 0.f),
                     fmaxf(fmaf(aE, dv, b3.z), 0.f), fmaxf(fmaf(aF, dv, b3.w), 0.f)};
        *(float4*)&out[(size_t)v * 128 + c0]      = o0;
        *(float4*)&out[(size_t)v * 128 + c0 + 4]  = o1;
        *(float4*)&out[(size_t)v * 128 + c0 + 8]  = o2;
        *(float4*)&out[(size_t)v * 128 + c0 + 12] = o3;
    }
}

// ---------- aggregation 64-col (final layer): wave = 8 edge-lanes x 8 feat-lanes ----------

__global__ __launch_bounds__(256) void aggregate64_kernel(const ushort_t* __restrict__ g,
                                                          const int* __restrict__ rowstart,
                                                          const int* __restrict__ csr_src,
                                                          const float* __restrict__ dinv,
                                                          const float* __restrict__ bias,
                                                          float* __restrict__ out, int n) {
    int wave = threadIdx.x >> 6;
    int lane = threadIdx.x & 63;
    int v = blockIdx.x * 4 + wave;
    if (v >= n) return;
    int s    = __builtin_amdgcn_readfirstlane(rowstart[v]);
    int epos = __builtin_amdgcn_readfirstlane(rowstart[v + 1]);
    int eg = lane >> 3;        // edge sub-lane 0..7
    int f  = lane & 7;         // feats f*8..f*8+7

    float a0 = 0.f, a1 = 0.f, a2 = 0.f, a3 = 0.f, a4 = 0.f, a5 = 0.f, a6 = 0.f, a7 = 0.f;
    if (lane < 8) {   // self row
        uint4 m = *(const uint4*)&g[(size_t)v * 64 + f * 8];
        a0 = bf2f_lo(m.x); a1 = bf2f_hi(m.x);
        a2 = bf2f_lo(m.y); a3 = bf2f_hi(m.y);
        a4 = bf2f_lo(m.z); a5 = bf2f_hi(m.z);
        a6 = bf2f_lo(m.w); a7 = bf2f_hi(m.w);
    }

    #pragma unroll 2
    for (int j = s; j < epos; j += 8) {
        int idx = j + eg;
        int safe = min(idx, epos - 1);
        int u = csr_src[safe];
        float w = (idx < epos) ? 1.f : 0.f;
        uint4 m = *(const uint4*)&g[(size_t)u * 64 + f * 8];
        a0 = fmaf(w, bf2f_lo(m.x), a0); a1 = fmaf(w, bf2f_hi(m.x), a1);
        a2 = fmaf(w, bf2f_lo(m.y), a2); a3 = fmaf(w, bf2f_hi(m.y), a3);
        a4 = fmaf(w, bf2f_lo(m.z), a4); a5 = fmaf(w, bf2f_hi(m.z), a5);
        a6 = fmaf(w, bf2f_lo(m.w), a6); a7 = fmaf(w, bf2f_hi(m.w), a7);
    }

    a0 += __shfl_xor(a0, 8);  a1 += __shfl_xor(a1, 8);
    a2 += __shfl_xor(a2, 8);  a3 += __shfl_xor(a3, 8);
    a4 += __shfl_xor(a4, 8);  a5 += __shfl_xor(a5, 8);
    a6 += __shfl_xor(a6, 8);  a7 += __shfl_xor(a7, 8);
    a0 += __shfl_xor(a0, 16); a1 += __shfl_xor(a1, 16);
    a2 += __shfl_xor(a2, 16); a3 += __shfl_xor(a3, 16);
    a4 += __shfl_xor(a4, 16); a5 += __shfl_xor(a5, 16);
    a6 += __shfl_xor(a6, 16); a7 += __shfl_xor(a7, 16);
    a0 += __shfl_xor(a0, 32); a1 += __shfl_xor(a1, 32);
    a2 += __shfl_xor(a2, 32); a3 += __shfl_xor(a3, 32);
    a4 += __shfl_xor(a4, 32); a5 += __shfl_xor(a5, 32);
    a6 += __shfl_xor(a6, 32); a7 += __shfl_xor(a7, 32);

    if (lane < 8) {
        float dv = dinv[v];
        float4 b0 = *(const float4*)&bias[f * 8];
        float4 b1 = *(const float4*)&bias[f * 8 + 4];
        float4 o0 = {fmaxf(fmaf(a0, dv, b0.x), 0.f), fmaxf(fmaf(a1, dv, b0.y), 0.f),
                     fmaxf(fmaf(a2, dv, b0.z), 0.f), fmaxf(fmaf(a3, dv, b0.w), 0.f)};
        float4 o1 = {fmaxf(fmaf(a4, dv, b1.x), 0.f), fmaxf(fmaf(a5, dv, b1.y), 0.f),
                     fmaxf(fmaf(a6, dv, b1.z), 0.f), fmaxf(fmaf(a7, dv, b1.w), 0.f)};
        *(float4*)&out[(size_t)v * 64 + f * 8] = o0;
        *(float4*)&out[(size_t)v * 64 + f * 8 + 4] = o1;
    }
}

extern "C" void kernel_launch(void* const* d_in, const int* in_sizes, int n_in,
                              void* d_out, int out_size, void* d_ws, size_t ws_size,
                              hipStream_t stream) {
    const float* x  = (const float*)d_in[0];
    const int*   ei = (const int*)d_in[1];   // [2, E] int32
    const float* W1 = (const float*)d_in[2];
    const float* b1 = (const float*)d_in[3];
    const float* W2 = (const float*)d_in[4];
    const float* b2 = (const float*)d_in[5];
    float* out = (float*)d_out;

    const int n = in_sizes[0] / 128;   // 50000 (<= 65536 required for packing)
    const int e = in_sizes[1] / 2;     // 800000
    const int* src = ei;
    const int* dst = ei + e;
    const int K   = (n + NPB - 1) / NPB;       // 782 buckets
    const int epb = (e + PB - 1) / PB;         // edges per chunk-block
    const int L   = K * PB;                    // flat histogram length

    char* ws = (char*)d_ws;
    size_t off = 0;
    auto carve = [&](size_t bytes) -> void* {
        void* p = ws + off;
        off = (off + bytes + 255) & ~(size_t)255;
        return p;
    };
    int*      hist     = (int*)     carve((size_t)L * 4);
    int*      bsum     = (int*)     carve((size_t)1024 * 4);
    int*      cnt      = (int*)     carve((size_t)n * 4);
    int*      rowstart = (int*)     carve((size_t)(n + 1) * 4);
    float*    dinv     = (float*)   carve((size_t)n * 4);
    uint_t*   ebuf     = (uint_t*)  carve((size_t)e * 4);
    int*      csr_src  = (int*)     carve((size_t)e * 4);
    ushort_t* g1       = (ushort_t*)carve((size_t)n * 128 * 2);
    float*    h2       = (float*)   carve((size_t)n * 128 * 4);
    ushort_t* g2       = (ushort_t*)carve((size_t)n * 64 * 2);
    (void)ws_size;

    const int nbL = (L + 1023) / 1024;   // hist scan blocks (<=256 required)
    const int nbN = (n + 1023) / 1024;   // node scan blocks (<=256 required)

    // --- CSR build, zero global atomics, zero memsets, 8 launches ---
    bucket_hist_kernel<<<PB, 256, 0, stream>>>(dst, e, epb, K, hist);
    block_sum_kernel<<<nbL, 256, 0, stream>>>(hist, L, bsum);
    local_scan_apply_kernel<<<nbL, 256, 0, stream>>>(hist, L, bsum, nbL);
    partition_kernel<<<PB, 256, 0, stream>>>(src, dst, e, epb, K, hist, ebuf);
    bucket_count_kernel<<<K, 256, 0, stream>>>(ebuf, hist, e, K, n, cnt);
    block_sum_kernel<<<nbN, 256, 0, stream>>>(cnt, n, bsum);
    local_scan_node_kernel<<<nbN, 256, 0, stream>>>(cnt, n, bsum, nbN, e, rowstart, dinv);
    bucket_fill_kernel<<<K, 256, 0, stream>>>(ebuf, hist, rowstart, e, K, n, csr_src);

    // --- layers ---
    const int gblocks = (n + 63) / 64;
    const int ablocks = (n + 3) / 4;
    gemm_scale_kernel<128><<<gblocks, 256, 0, stream>>>(x, W1, dinv, g1, n);
    aggregate128_kernel<<<ablocks, 256, 0, stream>>>(g1, rowstart, csr_src, dinv, b1, h2, n);
    gemm_scale_kernel<64><<<gblocks, 256, 0, stream>>>(h2, W2, dinv, g2, n);
    aggregate64_kernel<<<ablocks, 256, 0, stream>>>(g2, rowstart, csr_src, dinv, b2, out, n);
}

// Round 11
// 151.437 us; speedup vs baseline: 1.1269x; 1.0456x over previous
//
#include <hip/hip_runtime.h>

// GCN 2-layer for MI355X (gfx950). fp32 GEMM math, bf16 intermediates (g1, h2, g2).
// out[v] = relu( dinv[v]*( g[v] + sum_{u->v} g[u] ) + b ),  g = dinv .* (x @ W)
//
// R10 -> R11: gather is roofline'd (~7 TB/s line rate; R9/R10 evidence). This
// round attacks the rest: (1) h2 stored bf16 (saves ~25MB round-trip),
// (2) PB=256 (hist/partition were on half the chip), (3) nontemporal last-use
// streaming reads. CSR semantics untouched (R7-proven).
// Quarantined: R6 fused rowstart scan (replay nondeterminism); R9 agg+gemm fusion.
// R3 lesson: zero global atomics. R5 lesson: gather-form aggregation only.

#define NPB 64    // nodes per bucket (power of 2)
#define PB  256   // partition chunk-blocks (R11: 128->256, full-chip)

typedef unsigned short ushort_t;
typedef unsigned int uint_t;

__device__ inline float bf2f_lo(uint_t u) { return __uint_as_float(u << 16); }
__device__ inline float bf2f_hi(uint_t u) { return __uint_as_float(u & 0xffff0000u); }
__device__ inline ushort_t f2bf(float f) {   // round-to-nearest-even
    uint_t x = __float_as_uint(f);
    uint_t r = x + 0x7fffu + ((x >> 16) & 1u);
    return (ushort_t)(r >> 16);
}
__device__ inline uint_t pack2bf(float lo, float hi) {
    return (uint_t)f2bf(lo) | ((uint_t)f2bf(hi) << 16);
}

// ---------- scan machinery ----------

__global__ __launch_bounds__(256) void block_sum_kernel(const int* __restrict__ a, int L,
                                                        int* __restrict__ bsum) {
    __shared__ int red[256];
    int t = threadIdx.x;
    int base = blockIdx.x * 1024 + t * 4;
    int s = 0;
    if (base + 3 < L) {
        int4 v = *(const int4*)&a[base];
        s = v.x + v.y + v.z + v.w;
    } else {
        for (int i = 0; i < 4; ++i) if (base + i < L) s += a[base + i];
    }
    red[t] = s;
    __syncthreads();
    for (int off = 128; off > 0; off >>= 1) {
        if (t < off) red[t] += red[t + off];
        __syncthreads();
    }
    if (t == 0) bsum[blockIdx.x] = red[0];
}

// Merged: each block redundantly inclusive-scans bsum[0..nb-1] (nb<=256) in LDS,
// then does its local exclusive scan. In-place variant for the flat histogram.
__global__ __launch_bounds__(256) void local_scan_apply_kernel(int* __restrict__ arr, int L,
                                                               const int* __restrict__ bsum,
                                                               int nb) {
    __shared__ int sh[256];
    __shared__ int tsum[256];
    int b = blockIdx.x, t = threadIdx.x;
    sh[t] = (t < nb) ? bsum[t] : 0;
    __syncthreads();
    #pragma unroll
    for (int off = 1; off < 256; off <<= 1) {
        int w = (t >= off) ? sh[t - off] : 0;
        __syncthreads();
        sh[t] += w;
        __syncthreads();
    }
    int bprev = (b == 0) ? 0 : sh[b - 1];

    int base = b * 1024 + t * 4;
    int v[4];
    int s = 0;
    #pragma unroll
    for (int i = 0; i < 4; ++i) {
        int idx = base + i;
        v[i] = (idx < L) ? arr[idx] : 0;
        s += v[i];
    }
    tsum[t] = s;
    __syncthreads();
    for (int off = 1; off < 256; off <<= 1) {
        int w = (t >= off) ? tsum[t - off] : 0;
        __syncthreads();
        tsum[t] += w;
        __syncthreads();
    }
    int excl = (t == 0 ? 0 : tsum[t - 1]) + bprev;
    #pragma unroll
    for (int i = 0; i < 4; ++i) {
        int idx = base + i;
        if (idx < L) {
            arr[idx] = excl;
            excl += v[i];
        }
    }
}

// Merged node variant: cnt -> rowstart + dinv; also writes rowstart[n] = e.
__global__ __launch_bounds__(256) void local_scan_node_kernel(const int* __restrict__ cnt, int n,
                                                              const int* __restrict__ bsum,
                                                              int nb, int e_total,
                                                              int* __restrict__ rowstart,
                                                              float* __restrict__ dinv) {
    __shared__ int sh[256];
    __shared__ int tsum[256];
    int b = blockIdx.x, t = threadIdx.x;
    sh[t] = (t < nb) ? bsum[t] : 0;
    __syncthreads();
    #pragma unroll
    for (int off = 1; off < 256; off <<= 1) {
        int w = (t >= off) ? sh[t - off] : 0;
        __syncthreads();
        sh[t] += w;
        __syncthreads();
    }
    int bprev = (b == 0) ? 0 : sh[b - 1];

    int base = b * 1024 + t * 4;
    int v[4];
    int s = 0;
    #pragma unroll
    for (int i = 0; i < 4; ++i) {
        int idx = base + i;
        v[i] = (idx < n) ? cnt[idx] : 0;
        s += v[i];
    }
    tsum[t] = s;
    __syncthreads();
    for (int off = 1; off < 256; off <<= 1) {
        int w = (t >= off) ? tsum[t - off] : 0;
        __syncthreads();
        tsum[t] += w;
        __syncthreads();
    }
    int excl = (t == 0 ? 0 : tsum[t - 1]) + bprev;
    #pragma unroll
    for (int i = 0; i < 4; ++i) {
        int idx = base + i;
        if (idx < n) {
            rowstart[idx] = excl;
            excl += v[i];
            dinv[idx] = rsqrtf((float)(v[i] + 1));   // +1 self loop
        }
    }
    if (b == 0 && t == 0) rowstart[n] = e_total;
}

// ---------- radix partition (no global atomics) ----------

__global__ __launch_bounds__(256) void bucket_hist_kernel(const int* __restrict__ dst, int e,
                                                          int epb, int K,
                                                          int* __restrict__ hist) {
    __shared__ int lh[1024];
    int t = threadIdx.x, b = blockIdx.x;
    for (int k = t; k < K; k += 256) lh[k] = 0;
    __syncthreads();
    int lo = b * epb, hi = min(lo + epb, e);
    for (int i = lo + t; i < hi; i += 256) atomicAdd(&lh[dst[i] >> 6], 1);
    __syncthreads();
    for (int k = t; k < K; k += 256) hist[k * PB + b] = lh[k];
}

// scatter packed (src | dlocal<<16) into bucket regions (requires n <= 65536)
__global__ __launch_bounds__(256) void partition_kernel(const int* __restrict__ src,
                                                        const int* __restrict__ dst, int e,
                                                        int epb, int K,
                                                        const int* __restrict__ hist,
                                                        uint_t* __restrict__ ebuf) {
    __shared__ int loff[1024];
    int t = threadIdx.x, b = blockIdx.x;
    for (int k = t; k < K; k += 256) loff[k] = hist[k * PB + b];
    __syncthreads();
    int lo = b * epb, hi = min(lo + epb, e);
    for (int i = lo + t; i < hi; i += 256) {
        int d = dst[i];
        int k = d >> 6;
        int pos = atomicAdd(&loff[k], 1);   // LDS atomic only
        ebuf[pos] = (uint_t)src[i] | ((uint_t)(d & (NPB - 1)) << 16);
    }
}

// per-bucket node counts
__global__ __launch_bounds__(256) void bucket_count_kernel(const uint_t* __restrict__ ebuf,
                                                           const int* __restrict__ hist,
                                                           int e, int K, int n,
                                                           int* __restrict__ cnt) {
    __shared__ int c64[NPB];
    int t = threadIdx.x, k = blockIdx.x;
    if (t < NPB) c64[t] = 0;
    __syncthreads();
    int lo = hist[k * PB];
    int hi = (k + 1 < K) ? hist[(k + 1) * PB] : e;
    for (int i = lo + t; i < hi; i += 256) atomicAdd(&c64[(ebuf[i] >> 16) & (NPB - 1)], 1);
    __syncthreads();
    int node = k * NPB + t;
    if (t < NPB && node < n) cnt[node] = c64[t];
}

// per-bucket CSR fill: writes land in the bucket's ~4KB csr window.
// ebuf read is last-use -> nontemporal.
__global__ __launch_bounds__(256) void bucket_fill_kernel(const uint_t* __restrict__ ebuf,
                                                          const int* __restrict__ hist,
                                                          const int* __restrict__ rowstart,
                                                          int e, int K, int n,
                                                          int* __restrict__ csr_src) {
    __shared__ int rs[NPB];
    __shared__ int c64[NPB];
    int t = threadIdx.x, k = blockIdx.x;
    if (t < NPB) {
        int node = k * NPB + t;
        rs[t] = (node < n) ? rowstart[node] : 0;
        c64[t] = 0;
    }
    __syncthreads();
    int lo = hist[k * PB];
    int hi = (k + 1 < K) ? hist[(k + 1) * PB] : e;
    for (int i = lo + t; i < hi; i += 256) {
        uint_t u = __builtin_nontemporal_load(ebuf + i);
        int dl = (u >> 16) & (NPB - 1);
        int slot = rs[dl] + atomicAdd(&c64[dl], 1);   // LDS atomic only
        csr_src[slot] = (int)(u & 0xffffu);
    }
}

// ---------- GEMM (fp32 A input): C_bf16[n,COLS] = dinv[row]*(A[n,128]@W[128,COLS]) ----------
#define K_DIM 128
template <int COLS>
__global__ __launch_bounds__(256) void gemm_scale_kernel(const float* __restrict__ A,
                                                         const float* __restrict__ W,
                                                         const float* __restrict__ dinv,
                                                         ushort_t* __restrict__ out, int n) {
    constexpr int CG  = COLS / 4;
    constexpr int RG  = 256 / CG;
    constexpr int RPT = 64 / RG;
    __shared__ float Asl[64][132];   // 132*4B row stride: 16B aligned
    int t    = threadIdx.x;
    int row0 = blockIdx.x * 64;

    #pragma unroll
    for (int it = 0; it < 8; ++it) {
        int idx = (it * 256 + t) * 4;
        int r = idx >> 7;
        int k = idx & 127;
        int gr = row0 + r;
        float4 v = {0.f, 0.f, 0.f, 0.f};
        if (gr < n) v = *(const float4*)&A[gr * K_DIM + k];
        *(float4*)&Asl[r][k] = v;
    }
    __syncthreads();

    int cg = t % CG, rg = t / CG;
    int c0 = cg * 4;
    float acc[RPT][4];
    #pragma unroll
    for (int i = 0; i < RPT; ++i)
        for (int j = 0; j < 4; ++j) acc[i][j] = 0.f;

    const float4* W4 = (const float4*)W;
    constexpr int WS = COLS / 4;   // float4 per W row

    for (int k0 = 0; k0 < K_DIM; k0 += 4) {
        float4 w0 = W4[(k0 + 0) * WS + cg];
        float4 w1 = W4[(k0 + 1) * WS + cg];
        float4 w2 = W4[(k0 + 2) * WS + cg];
        float4 w3 = W4[(k0 + 3) * WS + cg];
        #pragma unroll
        for (int i = 0; i < RPT; ++i) {
            float4 a = *(const float4*)&Asl[rg * RPT + i][k0];
            acc[i][0] = fmaf(a.x, w0.x, acc[i][0]);
            acc[i][1] = fmaf(a.x, w0.y, acc[i][1]);
            acc[i][2] = fmaf(a.x, w0.z, acc[i][2]);
            acc[i][3] = fmaf(a.x, w0.w, acc[i][3]);
            acc[i][0] = fmaf(a.y, w1.x, acc[i][0]);
            acc[i][1] = fmaf(a.y, w1.y, acc[i][1]);
            acc[i][2] = fmaf(a.y, w1.z, acc[i][2]);
            acc[i][3] = fmaf(a.y, w1.w, acc[i][3]);
            acc[i][0] = fmaf(a.z, w2.x, acc[i][0]);
            acc[i][1] = fmaf(a.z, w2.y, acc[i][1]);
            acc[i][2] = fmaf(a.z, w2.z, acc[i][2]);
            acc[i][3] = fmaf(a.z, w2.w, acc[i][3]);
            acc[i][0] = fmaf(a.w, w3.x, acc[i][0]);
            acc[i][1] = fmaf(a.w, w3.y, acc[i][1]);
            acc[i][2] = fmaf(a.w, w3.z, acc[i][2]);
            acc[i][3] = fmaf(a.w, w3.w, acc[i][3]);
        }
    }

    #pragma unroll
    for (int i = 0; i < RPT; ++i) {
        int r = row0 + rg * RPT + i;
        if (r < n) {
            float s = dinv[r];
            ushort4 o;
            o.x = f2bf(acc[i][0] * s);
            o.y = f2bf(acc[i][1] * s);
            o.z = f2bf(acc[i][2] * s);
            o.w = f2bf(acc[i][3] * s);
            *(ushort4*)&out[r * COLS + c0] = o;
        }
    }
}

// ---------- GEMM (bf16 A input, COLS=64): g2 = dinv .* (h2_bf16 @ W2) ----------
__global__ __launch_bounds__(256) void gemm64_bf16_kernel(const ushort_t* __restrict__ A,
                                                          const float* __restrict__ W,
                                                          const float* __restrict__ dinv,
                                                          ushort_t* __restrict__ out, int n) {
    constexpr int COLS = 64;
    constexpr int CG  = COLS / 4;   // 16
    constexpr int RG  = 256 / CG;   // 16
    constexpr int RPT = 64 / RG;    // 4
    __shared__ float Asl[64][132];
    int t    = threadIdx.x;
    int row0 = blockIdx.x * 64;

    // stage: 64x128 bf16 -> fp32 LDS. 256 threads x 8 elems (uint4) x 4 iters.
    #pragma unroll
    for (int it = 0; it < 4; ++it) {
        int idx = (it * 256 + t) * 8;
        int r = idx >> 7;
        int k = idx & 127;
        int gr = row0 + r;
        uint4 v = {0u, 0u, 0u, 0u};
        if (gr < n) v = *(const uint4*)&A[gr * K_DIM + k];
        float4 fa = {bf2f_lo(v.x), bf2f_hi(v.x), bf2f_lo(v.y), bf2f_hi(v.y)};
        float4 fb = {bf2f_lo(v.z), bf2f_hi(v.z), bf2f_lo(v.w), bf2f_hi(v.w)};
        *(float4*)&Asl[r][k]     = fa;
        *(float4*)&Asl[r][k + 4] = fb;
    }
    __syncthreads();

    int cg = t % CG, rg = t / CG;
    int c0 = cg * 4;
    float acc[RPT][4];
    #pragma unroll
    for (int i = 0; i < RPT; ++i)
        for (int j = 0; j < 4; ++j) acc[i][j] = 0.f;

    const float4* W4 = (const float4*)W;
    constexpr int WS = COLS / 4;   // 16

    for (int k0 = 0; k0 < K_DIM; k0 += 4) {
        float4 w0 = W4[(k0 + 0) * WS + cg];
        float4 w1 = W4[(k0 + 1) * WS + cg];
        float4 w2 = W4[(k0 + 2) * WS + cg];
        float4 w3 = W4[(k0 + 3) * WS + cg];
        #pragma unroll
        for (int i = 0; i < RPT; ++i) {
            float4 a = *(const float4*)&Asl[rg * RPT + i][k0];
            acc[i][0] = fmaf(a.x, w0.x, acc[i][0]);
            acc[i][1] = fmaf(a.x, w0.y, acc[i][1]);
            acc[i][2] = fmaf(a.x, w0.z, acc[i][2]);
            acc[i][3] = fmaf(a.x, w0.w, acc[i][3]);
            acc[i][0] = fmaf(a.y, w1.x, acc[i][0]);
            acc[i][1] = fmaf(a.y, w1.y, acc[i][1]);
            acc[i][2] = fmaf(a.y, w1.z, acc[i][2]);
            acc[i][3] = fmaf(a.y, w1.w, acc[i][3]);
            acc[i][0] = fmaf(a.z, w2.x, acc[i][0]);
            acc[i][1] = fmaf(a.z, w2.y, acc[i][1]);
            acc[i][2] = fmaf(a.z, w2.z, acc[i][2]);
            acc[i][3] = fmaf(a.z, w2.w, acc[i][3]);
            acc[i][0] = fmaf(a.w, w3.x, acc[i][0]);
            acc[i][1] = fmaf(a.w, w3.y, acc[i][1]);
            acc[i][2] = fmaf(a.w, w3.z, acc[i][2]);
            acc[i][3] = fmaf(a.w, w3.w, acc[i][3]);
        }
    }

    #pragma unroll
    for (int i = 0; i < RPT; ++i) {
        int r = row0 + rg * RPT + i;
        if (r < n) {
            float s = dinv[r];
            ushort4 o;
            o.x = f2bf(acc[i][0] * s);
            o.y = f2bf(acc[i][1] * s);
            o.z = f2bf(acc[i][2] * s);
            o.w = f2bf(acc[i][3] * s);
            *(ushort4*)&out[r * COLS + c0] = o;
        }
    }
}

// ---------- aggregation 128-col: wave = 8 edge-lanes x 8 feat-lanes, 32B/lane ----------
// Output h2 in bf16 (R11).
__global__ __launch_bounds__(256) void aggregate128_kernel(const ushort_t* __restrict__ g,
                                                           const int* __restrict__ rowstart,
                                                           const int* __restrict__ csr_src,
                                                           const float* __restrict__ dinv,
                                                           const float* __restrict__ bias,
                                                           ushort_t* __restrict__ out, int n) {
    int wave = threadIdx.x >> 6;
    int lane = threadIdx.x & 63;
    int v = blockIdx.x * 4 + wave;
    if (v >= n) return;
    int s    = __builtin_amdgcn_readfirstlane(rowstart[v]);
    int epos = __builtin_amdgcn_readfirstlane(rowstart[v + 1]);
    int eg = lane >> 3;        // edge sub-lane 0..7
    int f  = lane & 7;         // feature group: feats f*16 .. f*16+15 (32B)

    float a0 = 0.f, a1 = 0.f, a2 = 0.f, a3 = 0.f, a4 = 0.f, a5 = 0.f, a6 = 0.f, a7 = 0.f;
    float a8 = 0.f, a9 = 0.f, aA = 0.f, aB = 0.f, aC = 0.f, aD = 0.f, aE = 0.f, aF = 0.f;
    if (lane < 8) {   // self row
        uint4 m0 = *(const uint4*)&g[(size_t)v * 128 + f * 16];
        uint4 m1 = *(const uint4*)&g[(size_t)v * 128 + f * 16 + 8];
        a0 = bf2f_lo(m0.x); a1 = bf2f_hi(m0.x);
        a2 = bf2f_lo(m0.y); a3 = bf2f_hi(m0.y);
        a4 = bf2f_lo(m0.z); a5 = bf2f_hi(m0.z);
        a6 = bf2f_lo(m0.w); a7 = bf2f_hi(m0.w);
        a8 = bf2f_lo(m1.x); a9 = bf2f_hi(m1.x);
        aA = bf2f_lo(m1.y); aB = bf2f_hi(m1.y);
        aC = bf2f_lo(m1.z); aD = bf2f_hi(m1.z);
        aE = bf2f_lo(m1.w); aF = bf2f_hi(m1.w);
    }

    #pragma unroll 2
    for (int j = s; j < epos; j += 8) {
        int idx = j + eg;
        int safe = min(idx, epos - 1);
        int u = csr_src[safe];
        float w = (idx < epos) ? 1.f : 0.f;
        uint4 m0 = *(const uint4*)&g[(size_t)u * 128 + f * 16];
        uint4 m1 = *(const uint4*)&g[(size_t)u * 128 + f * 16 + 8];
        a0 = fmaf(w, bf2f_lo(m0.x), a0); a1 = fmaf(w, bf2f_hi(m0.x), a1);
        a2 = fmaf(w, bf2f_lo(m0.y), a2); a3 = fmaf(w, bf2f_hi(m0.y), a3);
        a4 = fmaf(w, bf2f_lo(m0.z), a4); a5 = fmaf(w, bf2f_hi(m0.z), a5);
        a6 = fmaf(w, bf2f_lo(m0.w), a6); a7 = fmaf(w, bf2f_hi(m0.w), a7);
        a8 = fmaf(w, bf2f_lo(m1.x), a8); a9 = fmaf(w, bf2f_hi(m1.x), a9);
        aA = fmaf(w, bf2f_lo(m1.y), aA); aB = fmaf(w, bf2f_hi(m1.y), aB);
        aC = fmaf(w, bf2f_lo(m1.z), aC); aD = fmaf(w, bf2f_hi(m1.z), aD);
        aE = fmaf(w, bf2f_lo(m1.w), aE); aF = fmaf(w, bf2f_hi(m1.w), aF);
    }

    // combine 8 edge sub-lanes (xor over lane bits 3,4,5)
    #pragma unroll
    for (int m = 8; m <= 32; m <<= 1) {
        a0 += __shfl_xor(a0, m); a1 += __shfl_xor(a1, m);
        a2 += __shfl_xor(a2, m); a3 += __shfl_xor(a3, m);
        a4 += __shfl_xor(a4, m); a5 += __shfl_xor(a5, m);
        a6 += __shfl_xor(a6, m); a7 += __shfl_xor(a7, m);
        a8 += __shfl_xor(a8, m); a9 += __shfl_xor(a9, m);
        aA += __shfl_xor(aA, m); aB += __shfl_xor(aB, m);
        aC += __shfl_xor(aC, m); aD += __shfl_xor(aD, m);
        aE += __shfl_xor(aE, m); aF += __shfl_xor(aF, m);
    }

    if (lane < 8) {
        float dv = dinv[v];
        int c0 = f * 16;
        float4 b0 = *(const float4*)&bias[c0];
        float4 b1 = *(const float4*)&bias[c0 + 4];
        float4 b2 = *(const float4*)&bias[c0 + 8];
        float4 b3 = *(const float4*)&bias[c0 + 12];
        float o00 = fmaxf(fmaf(a0, dv, b0.x), 0.f), o01 = fmaxf(fmaf(a1, dv, b0.y), 0.f);
        float o02 = fmaxf(fmaf(a2, dv, b0.z), 0.f), o03 = fmaxf(fmaf(a3, dv, b0.w), 0.f);
        float o04 = fmaxf(fmaf(a4, dv, b1.x), 0.f), o05 = fmaxf(fmaf(a5, dv, b1.y), 0.f);
        float o06 = fmaxf(fmaf(a6, dv, b1.z), 0.f), o07 = fmaxf(fmaf(a7, dv, b1.w), 0.f);
        float o08 = fmaxf(fmaf(a8, dv, b2.x), 0.f), o09 = fmaxf(fmaf(a9, dv, b2.y), 0.f);
        float o10 = fmaxf(fmaf(aA, dv, b2.z), 0.f), o11 = fmaxf(fmaf(aB, dv, b2.w), 0.f);
        float o12 = fmaxf(fmaf(aC, dv, b3.x), 0.f), o13 = fmaxf(fmaf(aD, dv, b3.y), 0.f);
        float o14 = fmaxf(fmaf(aE, dv, b3.z), 0.f), o15 = fmaxf(fmaf(aF, dv, b3.w), 0.f);
        uint4 p0 = {pack2bf(o00, o01), pack2bf(o02, o03), pack2bf(o04, o05), pack2bf(o06, o07)};
        uint4 p1 = {pack2bf(o08, o09), pack2bf(o10, o11), pack2bf(o12, o13), pack2bf(o14, o15)};
        *(uint4*)&out[(size_t)v * 128 + c0]     = p0;
        *(uint4*)&out[(size_t)v * 128 + c0 + 8] = p1;
    }
}

// ---------- aggregation 64-col (final layer): wave = 8 edge-lanes x 8 feat-lanes ----------
// csr_src read is last-use -> nontemporal.
__global__ __launch_bounds__(256) void aggregate64_kernel(const ushort_t* __restrict__ g,
                                                          const int* __restrict__ rowstart,
                                                          const int* __restrict__ csr_src,
                                                          const float* __restrict__ dinv,
                                                          const float* __restrict__ bias,
                                                          float* __restrict__ out, int n) {
    int wave = threadIdx.x >> 6;
    int lane = threadIdx.x & 63;
    int v = blockIdx.x * 4 + wave;
    if (v >= n) return;
    int s    = __builtin_amdgcn_readfirstlane(rowstart[v]);
    int epos = __builtin_amdgcn_readfirstlane(rowstart[v + 1]);
    int eg = lane >> 3;        // edge sub-lane 0..7
    int f  = lane & 7;         // feats f*8..f*8+7

    float a0 = 0.f, a1 = 0.f, a2 = 0.f, a3 = 0.f, a4 = 0.f, a5 = 0.f, a6 = 0.f, a7 = 0.f;
    if (lane < 8) {   // self row
        uint4 m = *(const uint4*)&g[(size_t)v * 64 + f * 8];
        a0 = bf2f_lo(m.x); a1 = bf2f_hi(m.x);
        a2 = bf2f_lo(m.y); a3 = bf2f_hi(m.y);
        a4 = bf2f_lo(m.z); a5 = bf2f_hi(m.z);
        a6 = bf2f_lo(m.w); a7 = bf2f_hi(m.w);
    }

    #pragma unroll 2
    for (int j = s; j < epos; j += 8) {
        int idx = j + eg;
        int safe = min(idx, epos - 1);
        int u = __builtin_nontemporal_load(csr_src + safe);
        float w = (idx < epos) ? 1.f : 0.f;
        uint4 m = *(const uint4*)&g[(size_t)u * 64 + f * 8];
        a0 = fmaf(w, bf2f_lo(m.x), a0); a1 = fmaf(w, bf2f_hi(m.x), a1);
        a2 = fmaf(w, bf2f_lo(m.y), a2); a3 = fmaf(w, bf2f_hi(m.y), a3);
        a4 = fmaf(w, bf2f_lo(m.z), a4); a5 = fmaf(w, bf2f_hi(m.z), a5);
        a6 = fmaf(w, bf2f_lo(m.w), a6); a7 = fmaf(w, bf2f_hi(m.w), a7);
    }

    a0 += __shfl_xor(a0, 8);  a1 += __shfl_xor(a1, 8);
    a2 += __shfl_xor(a2, 8);  a3 += __shfl_xor(a3, 8);
    a4 += __shfl_xor(a4, 8);  a5 += __shfl_xor(a5, 8);
    a6 += __shfl_xor(a6, 8);  a7 += __shfl_xor(a7, 8);
    a0 += __shfl_xor(a0, 16); a1 += __shfl_xor(a1, 16);
    a2 += __shfl_xor(a2, 16); a3 += __shfl_xor(a3, 16);
    a4 += __shfl_xor(a4, 16); a5 += __shfl_xor(a5, 16);
    a6 += __shfl_xor(a6, 16); a7 += __shfl_xor(a7, 16);
    a0 += __shfl_xor(a0, 32); a1 += __shfl_xor(a1, 32);
    a2 += __shfl_xor(a2, 32); a3 += __shfl_xor(a3, 32);
    a4 += __shfl_xor(a4, 32); a5 += __shfl_xor(a5, 32);
    a6 += __shfl_xor(a6, 32); a7 += __shfl_xor(a7, 32);

    if (lane < 8) {
        float dv = dinv[v];
        float4 b0 = *(const float4*)&bias[f * 8];
        float4 b1 = *(const float4*)&bias[f * 8 + 4];
        float4 o0 = {fmaxf(fmaf(a0, dv, b0.x), 0.f), fmaxf(fmaf(a1, dv, b0.y), 0.f),
                     fmaxf(fmaf(a2, dv, b0.z), 0.f), fmaxf(fmaf(a3, dv, b0.w), 0.f)};
        float4 o1 = {fmaxf(fmaf(a4, dv, b1.x), 0.f), fmaxf(fmaf(a5, dv, b1.y), 0.f),
                     fmaxf(fmaf(a6, dv, b1.z), 0.f), fmaxf(fmaf(a7, dv, b1.w), 0.f)};
        *(float4*)&out[(size_t)v * 64 + f * 8] = o0;
        *(float4*)&out[(size_t)v * 64 + f * 8 + 4] = o1;
    }
}

extern "C" void kernel_launch(void* const* d_in, const int* in_sizes, int n_in,
                              void* d_out, int out_size, void* d_ws, size_t ws_size,
                              hipStream_t stream) {
    const float* x  = (const float*)d_in[0];
    const int*   ei = (const int*)d_in[1];   // [2, E] int32
    const float* W1 = (const float*)d_in[2];
    const float* b1 = (const float*)d_in[3];
    const float* W2 = (const float*)d_in[4];
    const float* b2 = (const float*)d_in[5];
    float* out = (float*)d_out;

    const int n = in_sizes[0] / 128;   // 50000 (<= 65536 required for packing)
    const int e = in_sizes[1] / 2;     // 800000
    const int* src = ei;
    const int* dst = ei + e;
    const int K   = (n + NPB - 1) / NPB;       // 782 buckets
    const int epb = (e + PB - 1) / PB;         // edges per chunk-block
    const int L   = K * PB;                    // flat histogram length

    char* ws = (char*)d_ws;
    size_t off = 0;
    auto carve = [&](size_t bytes) -> void* {
        void* p = ws + off;
        off = (off + bytes + 255) & ~(size_t)255;
        return p;
    };
    int*      hist     = (int*)     carve((size_t)L * 4);
    int*      bsum     = (int*)     carve((size_t)1024 * 4);
    int*      cnt      = (int*)     carve((size_t)n * 4);
    int*      rowstart = (int*)     carve((size_t)(n + 1) * 4);
    float*    dinv     = (float*)   carve((size_t)n * 4);
    uint_t*   ebuf     = (uint_t*)  carve((size_t)e * 4);
    int*      csr_src  = (int*)     carve((size_t)e * 4);
    ushort_t* g1       = (ushort_t*)carve((size_t)n * 128 * 2);
    ushort_t* h2       = (ushort_t*)carve((size_t)n * 128 * 2);   // bf16 (R11)
    ushort_t* g2       = (ushort_t*)carve((size_t)n * 64 * 2);
    (void)ws_size;

    const int nbL = (L + 1023) / 1024;   // hist scan blocks (196 <= 256 OK)
    const int nbN = (n + 1023) / 1024;   // node scan blocks (49 <= 256 OK)

    // --- CSR build, zero global atomics, zero memsets, 8 launches ---
    bucket_hist_kernel<<<PB, 256, 0, stream>>>(dst, e, epb, K, hist);
    block_sum_kernel<<<nbL, 256, 0, stream>>>(hist, L, bsum);
    local_scan_apply_kernel<<<nbL, 256, 0, stream>>>(hist, L, bsum, nbL);
    partition_kernel<<<PB, 256, 0, stream>>>(src, dst, e, epb, K, hist, ebuf);
    bucket_count_kernel<<<K, 256, 0, stream>>>(ebuf, hist, e, K, n, cnt);
    block_sum_kernel<<<nbN, 256, 0, stream>>>(cnt, n, bsum);
    local_scan_node_kernel<<<nbN, 256, 0, stream>>>(cnt, n, bsum, nbN, e, rowstart, dinv);
    bucket_fill_kernel<<<K, 256, 0, stream>>>(ebuf, hist, rowstart, e, K, n, csr_src);

    // --- layers ---
    const int gblocks = (n + 63) / 64;
    const int ablocks = (n + 3) / 4;
    gemm_scale_kernel<128><<<gblocks, 256, 0, stream>>>(x, W1, dinv, g1, n);
    aggregate128_kernel<<<ablocks, 256, 0, stream>>>(g1, rowstart, csr_src, dinv, b1, h2, n);
    gemm64_bf16_kernel<<<gblocks, 256, 0, stream>>>(h2, W2, dinv, g2, n);
    aggregate64_kernel<<<ablocks, 256, 0, stream>>>(g2, rowstart, csr_src, dinv, b2, out, n);
}

// Round 12
// 130.274 us; speedup vs baseline: 1.3100x; 1.1624x over previous
//
#include <hip/hip_runtime.h>

// GCN 2-layer for MI355X (gfx950). bf16 MFMA GEMMs (fp32 accum), bf16
// intermediates, fp32 out.
// out[v] = relu( dinv[v]*( g[v] + sum_{u->v} g[u] ) + b ),  g = dinv .* (x @ W)
//
// R11 -> R12: (1) both GEMMs moved to v_mfma_f32_16x16x32_bf16 (VALU GEMM was
// compute-bound at 157 TF; MFMA makes them staging-bound). W pre-converted to
// B-fragment layout by prep_w_kernel once. (2) csr_src stored as ushort
// (n<65536): halves csr traffic. CSR build semantics untouched (R7-proven).
// Aggregation untouched: rooflined at ~7 TB/s random-line rate (R9/R10).
// Quarantined: R6 fused rowstart scan; R9 agg+gemm fusion.

#define NPB 64    // nodes per bucket (power of 2)
#define PB  256   // partition chunk-blocks

typedef unsigned short ushort_t;
typedef unsigned int uint_t;
typedef __attribute__((ext_vector_type(8))) short bf16x8;   // 8 bf16 = 4 VGPRs
typedef __attribute__((ext_vector_type(4))) float f32x4;

__device__ inline float bf2f_lo(uint_t u) { return __uint_as_float(u << 16); }
__device__ inline float bf2f_hi(uint_t u) { return __uint_as_float(u & 0xffff0000u); }
__device__ inline ushort_t f2bf(float f) {   // round-to-nearest-even
    uint_t x = __float_as_uint(f);
    uint_t r = x + 0x7fffu + ((x >> 16) & 1u);
    return (ushort_t)(r >> 16);
}
__device__ inline uint_t pack2bf(float lo, float hi) {
    return (uint_t)f2bf(lo) | ((uint_t)f2bf(hi) << 16);
}

// ---------- W -> bf16 B-fragment layout (once per call) ----------
// frag[(ct*4+ks)*64 + kg*16 + lo][j] = W[ks*32 + kg*8 + j][ct*16 + lo]
__global__ __launch_bounds__(256) void prep_w_kernel(const float* __restrict__ W1,
                                                     const float* __restrict__ W2,
                                                     ushort_t* __restrict__ W1f,
                                                     ushort_t* __restrict__ W2f) {
    int i = blockIdx.x * 256 + threadIdx.x;
    if (i < 128 * 128) {
        int k = i >> 7, c = i & 127;
        int ct = c >> 4, lo = c & 15, ks = k >> 5, kg = (k >> 3) & 3, j = k & 7;
        W1f[(size_t)(((ct * 4 + ks) * 64) + kg * 16 + lo) * 8 + j] = f2bf(W1[i]);
    }
    if (i < 128 * 64) {
        int k = i >> 6, c = i & 63;
        int ct = c >> 4, lo = c & 15, ks = k >> 5, kg = (k >> 3) & 3, j = k & 7;
        W2f[(size_t)(((ct * 4 + ks) * 64) + kg * 16 + lo) * 8 + j] = f2bf(W2[i]);
    }
}

// ---------- scan machinery ----------

__global__ __launch_bounds__(256) void block_sum_kernel(const int* __restrict__ a, int L,
                                                        int* __restrict__ bsum) {
    __shared__ int red[256];
    int t = threadIdx.x;
    int base = blockIdx.x * 1024 + t * 4;
    int s = 0;
    if (base + 3 < L) {
        int4 v = *(const int4*)&a[base];
        s = v.x + v.y + v.z + v.w;
    } else {
        for (int i = 0; i < 4; ++i) if (base + i < L) s += a[base + i];
    }
    red[t] = s;
    __syncthreads();
    for (int off = 128; off > 0; off >>= 1) {
        if (t < off) red[t] += red[t + off];
        __syncthreads();
    }
    if (t == 0) bsum[blockIdx.x] = red[0];
}

__global__ __launch_bounds__(256) void local_scan_apply_kernel(int* __restrict__ arr, int L,
                                                               const int* __restrict__ bsum,
                                                               int nb) {
    __shared__ int sh[256];
    __shared__ int tsum[256];
    int b = blockIdx.x, t = threadIdx.x;
    sh[t] = (t < nb) ? bsum[t] : 0;
    __syncthreads();
    #pragma unroll
    for (int off = 1; off < 256; off <<= 1) {
        int w = (t >= off) ? sh[t - off] : 0;
        __syncthreads();
        sh[t] += w;
        __syncthreads();
    }
    int bprev = (b == 0) ? 0 : sh[b - 1];

    int base = b * 1024 + t * 4;
    int v[4];
    int s = 0;
    #pragma unroll
    for (int i = 0; i < 4; ++i) {
        int idx = base + i;
        v[i] = (idx < L) ? arr[idx] : 0;
        s += v[i];
    }
    tsum[t] = s;
    __syncthreads();
    for (int off = 1; off < 256; off <<= 1) {
        int w = (t >= off) ? tsum[t - off] : 0;
        __syncthreads();
        tsum[t] += w;
        __syncthreads();
    }
    int excl = (t == 0 ? 0 : tsum[t - 1]) + bprev;
    #pragma unroll
    for (int i = 0; i < 4; ++i) {
        int idx = base + i;
        if (idx < L) {
            arr[idx] = excl;
            excl += v[i];
        }
    }
}

__global__ __launch_bounds__(256) void local_scan_node_kernel(const int* __restrict__ cnt, int n,
                                                              const int* __restrict__ bsum,
                                                              int nb, int e_total,
                                                              int* __restrict__ rowstart,
                                                              float* __restrict__ dinv) {
    __shared__ int sh[256];
    __shared__ int tsum[256];
    int b = blockIdx.x, t = threadIdx.x;
    sh[t] = (t < nb) ? bsum[t] : 0;
    __syncthreads();
    #pragma unroll
    for (int off = 1; off < 256; off <<= 1) {
        int w = (t >= off) ? sh[t - off] : 0;
        __syncthreads();
        sh[t] += w;
        __syncthreads();
    }
    int bprev = (b == 0) ? 0 : sh[b - 1];

    int base = b * 1024 + t * 4;
    int v[4];
    int s = 0;
    #pragma unroll
    for (int i = 0; i < 4; ++i) {
        int idx = base + i;
        v[i] = (idx < n) ? cnt[idx] : 0;
        s += v[i];
    }
    tsum[t] = s;
    __syncthreads();
    for (int off = 1; off < 256; off <<= 1) {
        int w = (t >= off) ? tsum[t - off] : 0;
        __syncthreads();
        tsum[t] += w;
        __syncthreads();
    }
    int excl = (t == 0 ? 0 : tsum[t - 1]) + bprev;
    #pragma unroll
    for (int i = 0; i < 4; ++i) {
        int idx = base + i;
        if (idx < n) {
            rowstart[idx] = excl;
            excl += v[i];
            dinv[idx] = rsqrtf((float)(v[i] + 1));   // +1 self loop
        }
    }
    if (b == 0 && t == 0) rowstart[n] = e_total;
}

// ---------- radix partition (no global atomics) ----------

__global__ __launch_bounds__(256) void bucket_hist_kernel(const int* __restrict__ dst, int e,
                                                          int epb, int K,
                                                          int* __restrict__ hist) {
    __shared__ int lh[1024];
    int t = threadIdx.x, b = blockIdx.x;
    for (int k = t; k < K; k += 256) lh[k] = 0;
    __syncthreads();
    int lo = b * epb, hi = min(lo + epb, e);
    for (int i = lo + t; i < hi; i += 256) atomicAdd(&lh[dst[i] >> 6], 1);
    __syncthreads();
    for (int k = t; k < K; k += 256) hist[k * PB + b] = lh[k];
}

__global__ __launch_bounds__(256) void partition_kernel(const int* __restrict__ src,
                                                        const int* __restrict__ dst, int e,
                                                        int epb, int K,
                                                        const int* __restrict__ hist,
                                                        uint_t* __restrict__ ebuf) {
    __shared__ int loff[1024];
    int t = threadIdx.x, b = blockIdx.x;
    for (int k = t; k < K; k += 256) loff[k] = hist[k * PB + b];
    __syncthreads();
    int lo = b * epb, hi = min(lo + epb, e);
    for (int i = lo + t; i < hi; i += 256) {
        int d = dst[i];
        int k = d >> 6;
        int pos = atomicAdd(&loff[k], 1);   // LDS atomic only
        ebuf[pos] = (uint_t)src[i] | ((uint_t)(d & (NPB - 1)) << 16);
    }
}

__global__ __launch_bounds__(256) void bucket_count_kernel(const uint_t* __restrict__ ebuf,
                                                           const int* __restrict__ hist,
                                                           int e, int K, int n,
                                                           int* __restrict__ cnt) {
    __shared__ int c64[NPB];
    int t = threadIdx.x, k = blockIdx.x;
    if (t < NPB) c64[t] = 0;
    __syncthreads();
    int lo = hist[k * PB];
    int hi = (k + 1 < K) ? hist[(k + 1) * PB] : e;
    for (int i = lo + t; i < hi; i += 256) atomicAdd(&c64[(ebuf[i] >> 16) & (NPB - 1)], 1);
    __syncthreads();
    int node = k * NPB + t;
    if (t < NPB && node < n) cnt[node] = c64[t];
}

// csr stored as ushort (requires n <= 65536)
__global__ __launch_bounds__(256) void bucket_fill_kernel(const uint_t* __restrict__ ebuf,
                                                          const int* __restrict__ hist,
                                                          const int* __restrict__ rowstart,
                                                          int e, int K, int n,
                                                          ushort_t* __restrict__ csr_src) {
    __shared__ int rs[NPB];
    __shared__ int c64[NPB];
    int t = threadIdx.x, k = blockIdx.x;
    if (t < NPB) {
        int node = k * NPB + t;
        rs[t] = (node < n) ? rowstart[node] : 0;
        c64[t] = 0;
    }
    __syncthreads();
    int lo = hist[k * PB];
    int hi = (k + 1 < K) ? hist[(k + 1) * PB] : e;
    for (int i = lo + t; i < hi; i += 256) {
        uint_t u = __builtin_nontemporal_load(ebuf + i);
        int dl = (u >> 16) & (NPB - 1);
        int slot = rs[dl] + atomicAdd(&c64[dl], 1);   // LDS atomic only
        csr_src[slot] = (ushort_t)(u & 0xffffu);
    }
}

// ---------- MFMA GEMM 128-col: g1_bf16 = dinv .* (x_fp32 @ W1) ----------
// 64-row tile, 4 waves x (16 rows x 128 cols). A in padded LDS (272B stride).
__global__ __launch_bounds__(256) void gemm128_mfma_kernel(const float* __restrict__ A,
                                                           const ushort_t* __restrict__ Wf,
                                                           const float* __restrict__ dinv,
                                                           ushort_t* __restrict__ out, int n) {
    __shared__ ushort_t Asl[64][136];   // +8 pad: b128 reads land 2-way max
    int t = threadIdx.x;
    int row0 = blockIdx.x * 64;

    #pragma unroll
    for (int it = 0; it < 4; ++it) {
        int idx = (it * 256 + t) * 8;
        int r = idx >> 7, k = idx & 127;
        int gr = row0 + r;
        uint4 p = {0u, 0u, 0u, 0u};
        if (gr < n) {
            float4 lo = *(const float4*)&A[(size_t)gr * 128 + k];
            float4 hi = *(const float4*)&A[(size_t)gr * 128 + k + 4];
            p.x = pack2bf(lo.x, lo.y); p.y = pack2bf(lo.z, lo.w);
            p.z = pack2bf(hi.x, hi.y); p.w = pack2bf(hi.z, hi.w);
        }
        *(uint4*)&Asl[r][k] = p;
    }
    __syncthreads();

    int wave = t >> 6, lane = t & 63;
    int rb = wave * 16;
    int lrow = rb + (lane & 15);
    int kg8 = (lane >> 4) * 8;

    bf16x8 a0 = *(const bf16x8*)&Asl[lrow][0 * 32 + kg8];
    bf16x8 a1 = *(const bf16x8*)&Asl[lrow][1 * 32 + kg8];
    bf16x8 a2 = *(const bf16x8*)&Asl[lrow][2 * 32 + kg8];
    bf16x8 a3 = *(const bf16x8*)&Asl[lrow][3 * 32 + kg8];

    f32x4 acc[8];
    #pragma unroll
    for (int ct = 0; ct < 8; ++ct) acc[ct] = (f32x4){0.f, 0.f, 0.f, 0.f};

    #pragma unroll
    for (int ct = 0; ct < 8; ++ct) {
        const bf16x8* Wp = (const bf16x8*)&Wf[(size_t)(ct * 4) * 64 * 8];
        bf16x8 b0 = Wp[0 * 64 + lane];
        bf16x8 b1 = Wp[1 * 64 + lane];
        bf16x8 b2 = Wp[2 * 64 + lane];
        bf16x8 b3 = Wp[3 * 64 + lane];
        acc[ct] = __builtin_amdgcn_mfma_f32_16x16x32_bf16(a0, b0, acc[ct], 0, 0, 0);
        acc[ct] = __builtin_amdgcn_mfma_f32_16x16x32_bf16(a1, b1, acc[ct], 0, 0, 0);
        acc[ct] = __builtin_amdgcn_mfma_f32_16x16x32_bf16(a2, b2, acc[ct], 0, 0, 0);
        acc[ct] = __builtin_amdgcn_mfma_f32_16x16x32_bf16(a3, b3, acc[ct], 0, 0, 0);
    }

    // C/D: col = lane&15, row = (lane>>4)*4 + reg   [m89-verified]
    int orow0 = row0 + rb + (lane >> 4) * 4;
    int col0 = lane & 15;
    float dv[4];
    #pragma unroll
    for (int r = 0; r < 4; ++r) dv[r] = (orow0 + r < n) ? dinv[orow0 + r] : 0.f;
    #pragma unroll
    for (int ct = 0; ct < 8; ++ct) {
        #pragma unroll
        for (int r = 0; r < 4; ++r) {
            int row = orow0 + r;
            if (row < n) out[(size_t)row * 128 + ct * 16 + col0] = f2bf(acc[ct][r] * dv[r]);
        }
    }
}

// ---------- MFMA GEMM 64-col: g2_bf16 = dinv .* (h2_bf16 @ W2) ----------
__global__ __launch_bounds__(256) void gemm64_mfma_kernel(const ushort_t* __restrict__ A,
                                                          const ushort_t* __restrict__ Wf,
                                                          const float* __restrict__ dinv,
                                                          ushort_t* __restrict__ out, int n) {
    __shared__ ushort_t Asl[64][136];
    int t = threadIdx.x;
    int row0 = blockIdx.x * 64;

    #pragma unroll
    for (int it = 0; it < 4; ++it) {
        int idx = (it * 256 + t) * 8;
        int r = idx >> 7, k = idx & 127;
        int gr = row0 + r;
        uint4 p = {0u, 0u, 0u, 0u};
        if (gr < n) p = *(const uint4*)&A[(size_t)gr * 128 + k];
        *(uint4*)&Asl[r][k] = p;
    }
    __syncthreads();

    int wave = t >> 6, lane = t & 63;
    int rb = wave * 16;
    int lrow = rb + (lane & 15);
    int kg8 = (lane >> 4) * 8;

    bf16x8 a0 = *(const bf16x8*)&Asl[lrow][0 * 32 + kg8];
    bf16x8 a1 = *(const bf16x8*)&Asl[lrow][1 * 32 + kg8];
    bf16x8 a2 = *(const bf16x8*)&Asl[lrow][2 * 32 + kg8];
    bf16x8 a3 = *(const bf16x8*)&Asl[lrow][3 * 32 + kg8];

    f32x4 acc[4];
    #pragma unroll
    for (int ct = 0; ct < 4; ++ct) acc[ct] = (f32x4){0.f, 0.f, 0.f, 0.f};

    #pragma unroll
    for (int ct = 0; ct < 4; ++ct) {
        const bf16x8* Wp = (const bf16x8*)&Wf[(size_t)(ct * 4) * 64 * 8];
        bf16x8 b0 = Wp[0 * 64 + lane];
        bf16x8 b1 = Wp[1 * 64 + lane];
        bf16x8 b2 = Wp[2 * 64 + lane];
        bf16x8 b3 = Wp[3 * 64 + lane];
        acc[ct] = __builtin_amdgcn_mfma_f32_16x16x32_bf16(a0, b0, acc[ct], 0, 0, 0);
        acc[ct] = __builtin_amdgcn_mfma_f32_16x16x32_bf16(a1, b1, acc[ct], 0, 0, 0);
        acc[ct] = __builtin_amdgcn_mfma_f32_16x16x32_bf16(a2, b2, acc[ct], 0, 0, 0);
        acc[ct] = __builtin_amdgcn_mfma_f32_16x16x32_bf16(a3, b3, acc[ct], 0, 0, 0);
    }

    int orow0 = row0 + rb + (lane >> 4) * 4;
    int col0 = lane & 15;
    float dv[4];
    #pragma unroll
    for (int r = 0; r < 4; ++r) dv[r] = (orow0 + r < n) ? dinv[orow0 + r] : 0.f;
    #pragma unroll
    for (int ct = 0; ct < 4; ++ct) {
        #pragma unroll
        for (int r = 0; r < 4; ++r) {
            int row = orow0 + r;
            if (row < n) out[(size_t)row * 64 + ct * 16 + col0] = f2bf(acc[ct][r] * dv[r]);
        }
    }
}

// ---------- aggregation 128-col: wave = 8 edge-lanes x 8 feat-lanes, 32B/lane ----------
__global__ __launch_bounds__(256) void aggregate128_kernel(const ushort_t* __restrict__ g,
                                                           const int* __restrict__ rowstart,
                                                           const ushort_t* __restrict__ csr_src,
                                                           const float* __restrict__ dinv,
                                                           const float* __restrict__ bias,
                                                           ushort_t* __restrict__ out, int n) {
    int wave = threadIdx.x >> 6;
    int lane = threadIdx.x & 63;
    int v = blockIdx.x * 4 + wave;
    if (v >= n) return;
    int s    = __builtin_amdgcn_readfirstlane(rowstart[v]);
    int epos = __builtin_amdgcn_readfirstlane(rowstart[v + 1]);
    int eg = lane >> 3;        // edge sub-lane 0..7
    int f  = lane & 7;         // feature group: feats f*16 .. f*16+15 (32B)

    float a0 = 0.f, a1 = 0.f, a2 = 0.f, a3 = 0.f, a4 = 0.f, a5 = 0.f, a6 = 0.f, a7 = 0.f;
    float a8 = 0.f, a9 = 0.f, aA = 0.f, aB = 0.f, aC = 0.f, aD = 0.f, aE = 0.f, aF = 0.f;
    if (lane < 8) {   // self row
        uint4 m0 = *(const uint4*)&g[(size_t)v * 128 + f * 16];
        uint4 m1 = *(const uint4*)&g[(size_t)v * 128 + f * 16 + 8];
        a0 = bf2f_lo(m0.x); a1 = bf2f_hi(m0.x);
        a2 = bf2f_lo(m0.y); a3 = bf2f_hi(m0.y);
        a4 = bf2f_lo(m0.z); a5 = bf2f_hi(m0.z);
        a6 = bf2f_lo(m0.w); a7 = bf2f_hi(m0.w);
        a8 = bf2f_lo(m1.x); a9 = bf2f_hi(m1.x);
        aA = bf2f_lo(m1.y); aB = bf2f_hi(m1.y);
        aC = bf2f_lo(m1.z); aD = bf2f_hi(m1.z);
        aE = bf2f_lo(m1.w); aF = bf2f_hi(m1.w);
    }

    #pragma unroll 2
    for (int j = s; j < epos; j += 8) {
        int idx = j + eg;
        int safe = min(idx, epos - 1);
        int u = csr_src[safe];
        float w = (idx < epos) ? 1.f : 0.f;
        uint4 m0 = *(const uint4*)&g[(size_t)u * 128 + f * 16];
        uint4 m1 = *(const uint4*)&g[(size_t)u * 128 + f * 16 + 8];
        a0 = fmaf(w, bf2f_lo(m0.x), a0); a1 = fmaf(w, bf2f_hi(m0.x), a1);
        a2 = fmaf(w, bf2f_lo(m0.y), a2); a3 = fmaf(w, bf2f_hi(m0.y), a3);
        a4 = fmaf(w, bf2f_lo(m0.z), a4); a5 = fmaf(w, bf2f_hi(m0.z), a5);
        a6 = fmaf(w, bf2f_lo(m0.w), a6); a7 = fmaf(w, bf2f_hi(m0.w), a7);
        a8 = fmaf(w, bf2f_lo(m1.x), a8); a9 = fmaf(w, bf2f_hi(m1.x), a9);
        aA = fmaf(w, bf2f_lo(m1.y), aA); aB = fmaf(w, bf2f_hi(m1.y), aB);
        aC = fmaf(w, bf2f_lo(m1.z), aC); aD = fmaf(w, bf2f_hi(m1.z), aD);
        aE = fmaf(w, bf2f_lo(m1.w), aE); aF = fmaf(w, bf2f_hi(m1.w), aF);
    }

    #pragma unroll
    for (int m = 8; m <= 32; m <<= 1) {
        a0 += __shfl_xor(a0, m); a1 += __shfl_xor(a1, m);
        a2 += __shfl_xor(a2, m); a3 += __shfl_xor(a3, m);
        a4 += __shfl_xor(a4, m); a5 += __shfl_xor(a5, m);
        a6 += __shfl_xor(a6, m); a7 += __shfl_xor(a7, m);
        a8 += __shfl_xor(a8, m); a9 += __shfl_xor(a9, m);
        aA += __shfl_xor(aA, m); aB += __shfl_xor(aB, m);
        aC += __shfl_xor(aC, m); aD += __shfl_xor(aD, m);
        aE += __shfl_xor(aE, m); aF += __shfl_xor(aF, m);
    }

    if (lane < 8) {
        float dv = dinv[v];
        int c0 = f * 16;
        float4 b0 = *(const float4*)&bias[c0];
        float4 b1 = *(const float4*)&bias[c0 + 4];
        float4 b2 = *(const float4*)&bias[c0 + 8];
        float4 b3 = *(const float4*)&bias[c0 + 12];
        float o00 = fmaxf(fmaf(a0, dv, b0.x), 0.f), o01 = fmaxf(fmaf(a1, dv, b0.y), 0.f);
        float o02 = fmaxf(fmaf(a2, dv, b0.z), 0.f), o03 = fmaxf(fmaf(a3, dv, b0.w), 0.f);
        float o04 = fmaxf(fmaf(a4, dv, b1.x), 0.f), o05 = fmaxf(fmaf(a5, dv, b1.y), 0.f);
        float o06 = fmaxf(fmaf(a6, dv, b1.z), 0.f), o07 = fmaxf(fmaf(a7, dv, b1.w), 0.f);
        float o08 = fmaxf(fmaf(a8, dv, b2.x), 0.f), o09 = fmaxf(fmaf(a9, dv, b2.y), 0.f);
        float o10 = fmaxf(fmaf(aA, dv, b2.z), 0.f), o11 = fmaxf(fmaf(aB, dv, b2.w), 0.f);
        float o12 = fmaxf(fmaf(aC, dv, b3.x), 0.f), o13 = fmaxf(fmaf(aD, dv, b3.y), 0.f);
        float o14 = fmaxf(fmaf(aE, dv, b3.z), 0.f), o15 = fmaxf(fmaf(aF, dv, b3.w), 0.f);
        uint4 p0 = {pack2bf(o00, o01), pack2bf(o02, o03), pack2bf(o04, o05), pack2bf(o06, o07)};
        uint4 p1 = {pack2bf(o08, o09), pack2bf(o10, o11), pack2bf(o12, o13), pack2bf(o14, o15)};
        *(uint4*)&out[(size_t)v * 128 + c0]     = p0;
        *(uint4*)&out[(size_t)v * 128 + c0 + 8] = p1;
    }
}

// ---------- aggregation 64-col (final layer) ----------
__global__ __launch_bounds__(256) void aggregate64_kernel(const ushort_t* __restrict__ g,
                                                          const int* __restrict__ rowstart,
                                                          const ushort_t* __restrict__ csr_src,
                                                          const float* __restrict__ dinv,
                                                          const float* __restrict__ bias,
                                                          float* __restrict__ out, int n) {
    int wave = threadIdx.x >> 6;
    int lane = threadIdx.x & 63;
    int v = blockIdx.x * 4 + wave;
    if (v >= n) return;
    int s    = __builtin_amdgcn_readfirstlane(rowstart[v]);
    int epos = __builtin_amdgcn_readfirstlane(rowstart[v + 1]);
    int eg = lane >> 3;        // edge sub-lane 0..7
    int f  = lane & 7;         // feats f*8..f*8+7

    float a0 = 0.f, a1 = 0.f, a2 = 0.f, a3 = 0.f, a4 = 0.f, a5 = 0.f, a6 = 0.f, a7 = 0.f;
    if (lane < 8) {   // self row
        uint4 m = *(const uint4*)&g[(size_t)v * 64 + f * 8];
        a0 = bf2f_lo(m.x); a1 = bf2f_hi(m.x);
        a2 = bf2f_lo(m.y); a3 = bf2f_hi(m.y);
        a4 = bf2f_lo(m.z); a5 = bf2f_hi(m.z);
        a6 = bf2f_lo(m.w); a7 = bf2f_hi(m.w);
    }

    #pragma unroll 2
    for (int j = s; j < epos; j += 8) {
        int idx = j + eg;
        int safe = min(idx, epos - 1);
        int u = __builtin_nontemporal_load(csr_src + safe);
        float w = (idx < epos) ? 1.f : 0.f;
        uint4 m = *(const uint4*)&g[(size_t)u * 64 + f * 8];
        a0 = fmaf(w, bf2f_lo(m.x), a0); a1 = fmaf(w, bf2f_hi(m.x), a1);
        a2 = fmaf(w, bf2f_lo(m.y), a2); a3 = fmaf(w, bf2f_hi(m.y), a3);
        a4 = fmaf(w, bf2f_lo(m.z), a4); a5 = fmaf(w, bf2f_hi(m.z), a5);
        a6 = fmaf(w, bf2f_lo(m.w), a6); a7 = fmaf(w, bf2f_hi(m.w), a7);
    }

    a0 += __shfl_xor(a0, 8);  a1 += __shfl_xor(a1, 8);
    a2 += __shfl_xor(a2, 8);  a3 += __shfl_xor(a3, 8);
    a4 += __shfl_xor(a4, 8);  a5 += __shfl_xor(a5, 8);
    a6 += __shfl_xor(a6, 8);  a7 += __shfl_xor(a7, 8);
    a0 += __shfl_xor(a0, 16); a1 += __shfl_xor(a1, 16);
    a2 += __shfl_xor(a2, 16); a3 += __shfl_xor(a3, 16);
    a4 += __shfl_xor(a4, 16); a5 += __shfl_xor(a5, 16);
    a6 += __shfl_xor(a6, 16); a7 += __shfl_xor(a7, 16);
    a0 += __shfl_xor(a0, 32); a1 += __shfl_xor(a1, 32);
    a2 += __shfl_xor(a2, 32); a3 += __shfl_xor(a3, 32);
    a4 += __shfl_xor(a4, 32); a5 += __shfl_xor(a5, 32);
    a6 += __shfl_xor(a6, 32); a7 += __shfl_xor(a7, 32);

    if (lane < 8) {
        float dv = dinv[v];
        float4 b0 = *(const float4*)&bias[f * 8];
        float4 b1 = *(const float4*)&bias[f * 8 + 4];
        float4 o0 = {fmaxf(fmaf(a0, dv, b0.x), 0.f), fmaxf(fmaf(a1, dv, b0.y), 0.f),
                     fmaxf(fmaf(a2, dv, b0.z), 0.f), fmaxf(fmaf(a3, dv, b0.w), 0.f)};
        float4 o1 = {fmaxf(fmaf(a4, dv, b1.x), 0.f), fmaxf(fmaf(a5, dv, b1.y), 0.f),
                     fmaxf(fmaf(a6, dv, b1.z), 0.f), fmaxf(fmaf(a7, dv, b1.w), 0.f)};
        *(float4*)&out[(size_t)v * 64 + f * 8] = o0;
        *(float4*)&out[(size_t)v * 64 + f * 8 + 4] = o1;
    }
}

extern "C" void kernel_launch(void* const* d_in, const int* in_sizes, int n_in,
                              void* d_out, int out_size, void* d_ws, size_t ws_size,
                              hipStream_t stream) {
    const float* x  = (const float*)d_in[0];
    const int*   ei = (const int*)d_in[1];   // [2, E] int32
    const float* W1 = (const float*)d_in[2];
    const float* b1 = (const float*)d_in[3];
    const float* W2 = (const float*)d_in[4];
    const float* b2 = (const float*)d_in[5];
    float* out = (float*)d_out;

    const int n = in_sizes[0] / 128;   // 50000 (<= 65536 required for packing)
    const int e = in_sizes[1] / 2;     // 800000
    const int* src = ei;
    const int* dst = ei + e;
    const int K   = (n + NPB - 1) / NPB;       // 782 buckets
    const int epb = (e + PB - 1) / PB;         // edges per chunk-block
    const int L   = K * PB;                    // flat histogram length

    char* ws = (char*)d_ws;
    size_t off = 0;
    auto carve = [&](size_t bytes) -> void* {
        void* p = ws + off;
        off = (off + bytes + 255) & ~(size_t)255;
        return p;
    };
    int*      hist     = (int*)     carve((size_t)L * 4);
    int*      bsum     = (int*)     carve((size_t)1024 * 4);
    int*      cnt      = (int*)     carve((size_t)n * 4);
    int*      rowstart = (int*)     carve((size_t)(n + 1) * 4);
    float*    dinv     = (float*)   carve((size_t)n * 4);
    uint_t*   ebuf     = (uint_t*)  carve((size_t)e * 4);
    ushort_t* csr_src  = (ushort_t*)carve((size_t)e * 2);
    ushort_t* W1f      = (ushort_t*)carve((size_t)128 * 128 * 2);
    ushort_t* W2f      = (ushort_t*)carve((size_t)128 * 64 * 2);
    ushort_t* g1       = (ushort_t*)carve((size_t)n * 128 * 2);
    ushort_t* h2       = (ushort_t*)carve((size_t)n * 128 * 2);
    ushort_t* g2       = (ushort_t*)carve((size_t)n * 64 * 2);
    (void)ws_size;

    const int nbL = (L + 1023) / 1024;   // hist scan blocks (196 <= 256 OK)
    const int nbN = (n + 1023) / 1024;   // node scan blocks (49 <= 256 OK)

    // --- W fragment prep + CSR build (zero global atomics, zero memsets) ---
    prep_w_kernel<<<64, 256, 0, stream>>>(W1, W2, W1f, W2f);
    bucket_hist_kernel<<<PB, 256, 0, stream>>>(dst, e, epb, K, hist);
    block_sum_kernel<<<nbL, 256, 0, stream>>>(hist, L, bsum);
    local_scan_apply_kernel<<<nbL, 256, 0, stream>>>(hist, L, bsum, nbL);
    partition_kernel<<<PB, 256, 0, stream>>>(src, dst, e, epb, K, hist, ebuf);
    bucket_count_kernel<<<K, 256, 0, stream>>>(ebuf, hist, e, K, n, cnt);
    block_sum_kernel<<<nbN, 256, 0, stream>>>(cnt, n, bsum);
    local_scan_node_kernel<<<nbN, 256, 0, stream>>>(cnt, n, bsum, nbN, e, rowstart, dinv);
    bucket_fill_kernel<<<K, 256, 0, stream>>>(ebuf, hist, rowstart, e, K, n, csr_src);

    // --- layers ---
    const int gblocks = (n + 63) / 64;
    const int ablocks = (n + 3) / 4;
    gemm128_mfma_kernel<<<gblocks, 256, 0, stream>>>(x, W1f, dinv, g1, n);
    aggregate128_kernel<<<ablocks, 256, 0, stream>>>(g1, rowstart, csr_src, dinv, b1, h2, n);
    gemm64_mfma_kernel<<<gblocks, 256, 0, stream>>>(h2, W2f, dinv, g2, n);
    aggregate64_kernel<<<ablocks, 256, 0, stream>>>(g2, rowstart, csr_src, dinv, b2, out, n);
}

// Round 13
// 121.007 us; speedup vs baseline: 1.4103x; 1.0766x over previous
//
#include <hip/hip_runtime.h>

// GCN 2-layer for MI355X (gfx950). bf16 MFMA GEMMs (fp32 accum), bf16
// intermediates, fp32 out.
// out[v] = relu( dinv[v]*( g[v] + sum_{u->v} g[u] ) + b ),  g = dinv .* (x @ W)
//
// R12 -> R13 (10 launches, was 13):
//  1) node block_sum deleted: local_scan_node's cross-block base is read
//     directly from the scanned hist (hist[(16*blk)*PB] = edges before bucket).
//  2) prep_w folded into bucket_hist (first 64 blocks also convert W).
//  3) agg128+gemm64 fused with MFMA: 16 nodes/block, h2 lives in 4.3KB LDS
//     (never HBM), W2f fragment reuse = 50MB L2 total (vs R9's 400MB mistake).
// Aggregation gather rooflined at ~7 TB/s line rate (R9/R10). CSR count->
// scan->fill structure unchanged (R7-proven). Quarantined: R6 in-kernel
// rowstart shfl-scan; R9 VALU fusion.

#define NPB 64    // nodes per bucket (power of 2)
#define PB  256   // partition chunk-blocks

typedef unsigned short ushort_t;
typedef unsigned int uint_t;
typedef __attribute__((ext_vector_type(8))) short bf16x8;   // 8 bf16 = 4 VGPRs
typedef __attribute__((ext_vector_type(4))) float f32x4;

__device__ inline float bf2f_lo(uint_t u) { return __uint_as_float(u << 16); }
__device__ inline float bf2f_hi(uint_t u) { return __uint_as_float(u & 0xffff0000u); }
__device__ inline ushort_t f2bf(float f) {   // round-to-nearest-even
    uint_t x = __float_as_uint(f);
    uint_t r = x + 0x7fffu + ((x >> 16) & 1u);
    return (ushort_t)(r >> 16);
}
__device__ inline uint_t pack2bf(float lo, float hi) {
    return (uint_t)f2bf(lo) | ((uint_t)f2bf(hi) << 16);
}

// ---------- scan machinery (hist path only) ----------

__global__ __launch_bounds__(256) void block_sum_kernel(const int* __restrict__ a, int L,
                                                        int* __restrict__ bsum) {
    __shared__ int red[256];
    int t = threadIdx.x;
    int base = blockIdx.x * 1024 + t * 4;
    int s = 0;
    if (base + 3 < L) {
        int4 v = *(const int4*)&a[base];
        s = v.x + v.y + v.z + v.w;
    } else {
        for (int i = 0; i < 4; ++i) if (base + i < L) s += a[base + i];
    }
    red[t] = s;
    __syncthreads();
    for (int off = 128; off > 0; off >>= 1) {
        if (t < off) red[t] += red[t + off];
        __syncthreads();
    }
    if (t == 0) bsum[blockIdx.x] = red[0];
}

__global__ __launch_bounds__(256) void local_scan_apply_kernel(int* __restrict__ arr, int L,
                                                               const int* __restrict__ bsum,
                                                               int nb) {
    __shared__ int sh[256];
    __shared__ int tsum[256];
    int b = blockIdx.x, t = threadIdx.x;
    sh[t] = (t < nb) ? bsum[t] : 0;
    __syncthreads();
    #pragma unroll
    for (int off = 1; off < 256; off <<= 1) {
        int w = (t >= off) ? sh[t - off] : 0;
        __syncthreads();
        sh[t] += w;
        __syncthreads();
    }
    int bprev = (b == 0) ? 0 : sh[b - 1];

    int base = b * 1024 + t * 4;
    int v[4];
    int s = 0;
    #pragma unroll
    for (int i = 0; i < 4; ++i) {
        int idx = base + i;
        v[i] = (idx < L) ? arr[idx] : 0;
        s += v[i];
    }
    tsum[t] = s;
    __syncthreads();
    for (int off = 1; off < 256; off <<= 1) {
        int w = (t >= off) ? tsum[t - off] : 0;
        __syncthreads();
        tsum[t] += w;
        __syncthreads();
    }
    int excl = (t == 0 ? 0 : tsum[t - 1]) + bprev;
    #pragma unroll
    for (int i = 0; i < 4; ++i) {
        int idx = base + i;
        if (idx < L) {
            arr[idx] = excl;
            excl += v[i];
        }
    }
}

// Node scan: cross-block base read directly from scanned hist (R13).
// Block b covers nodes [1024b, 1024b+1024) = buckets [16b, 16b+16);
// edges before bucket 16b = hist_scanned[(16b)*PB]  (hist[0] == 0).
__global__ __launch_bounds__(256) void local_scan_node_kernel(const int* __restrict__ cnt, int n,
                                                              const int* __restrict__ hist,
                                                              int e_total,
                                                              int* __restrict__ rowstart,
                                                              float* __restrict__ dinv) {
    __shared__ int tsum[256];
    int b = blockIdx.x, t = threadIdx.x;
    int bprev = hist[(size_t)(b * 16) * PB];

    int base = b * 1024 + t * 4;
    int v[4];
    int s = 0;
    #pragma unroll
    for (int i = 0; i < 4; ++i) {
        int idx = base + i;
        v[i] = (idx < n) ? cnt[idx] : 0;
        s += v[i];
    }
    tsum[t] = s;
    __syncthreads();
    for (int off = 1; off < 256; off <<= 1) {
        int w = (t >= off) ? tsum[t - off] : 0;
        __syncthreads();
        tsum[t] += w;
        __syncthreads();
    }
    int excl = (t == 0 ? 0 : tsum[t - 1]) + bprev;
    #pragma unroll
    for (int i = 0; i < 4; ++i) {
        int idx = base + i;
        if (idx < n) {
            rowstart[idx] = excl;
            excl += v[i];
            dinv[idx] = rsqrtf((float)(v[i] + 1));   // +1 self loop
        }
    }
    if (b == 0 && t == 0) rowstart[n] = e_total;
}

// ---------- radix partition (no global atomics) ----------

// Also performs the one-time W -> bf16 B-fragment conversion (R13 fold):
// frag[(ct*4+ks)*64 + kg*16 + lo][j] = W[ks*32 + kg*8 + j][ct*16 + lo]
__global__ __launch_bounds__(256) void bucket_hist_kernel(const int* __restrict__ dst, int e,
                                                          int epb, int K,
                                                          int* __restrict__ hist,
                                                          const float* __restrict__ W1,
                                                          const float* __restrict__ W2,
                                                          ushort_t* __restrict__ W1f,
                                                          ushort_t* __restrict__ W2f) {
    int t = threadIdx.x, b = blockIdx.x;
    int gi = b * 256 + t;
    if (gi < 128 * 128) {
        int k = gi >> 7, c = gi & 127;
        int ct = c >> 4, lo = c & 15, ks = k >> 5, kg = (k >> 3) & 3, j = k & 7;
        W1f[(size_t)(((ct * 4 + ks) * 64) + kg * 16 + lo) * 8 + j] = f2bf(W1[gi]);
    }
    if (gi < 128 * 64) {
        int k = gi >> 6, c = gi & 63;
        int ct = c >> 4, lo = c & 15, ks = k >> 5, kg = (k >> 3) & 3, j = k & 7;
        W2f[(size_t)(((ct * 4 + ks) * 64) + kg * 16 + lo) * 8 + j] = f2bf(W2[gi]);
    }

    __shared__ int lh[1024];
    for (int k = t; k < K; k += 256) lh[k] = 0;
    __syncthreads();
    int lo = b * epb, hi = min(lo + epb, e);
    for (int i = lo + t; i < hi; i += 256) atomicAdd(&lh[dst[i] >> 6], 1);
    __syncthreads();
    for (int k = t; k < K; k += 256) hist[k * PB + b] = lh[k];
}

__global__ __launch_bounds__(256) void partition_kernel(const int* __restrict__ src,
                                                        const int* __restrict__ dst, int e,
                                                        int epb, int K,
                                                        const int* __restrict__ hist,
                                                        uint_t* __restrict__ ebuf) {
    __shared__ int loff[1024];
    int t = threadIdx.x, b = blockIdx.x;
    for (int k = t; k < K; k += 256) loff[k] = hist[k * PB + b];
    __syncthreads();
    int lo = b * epb, hi = min(lo + epb, e);
    for (int i = lo + t; i < hi; i += 256) {
        int d = dst[i];
        int k = d >> 6;
        int pos = atomicAdd(&loff[k], 1);   // LDS atomic only
        ebuf[pos] = (uint_t)src[i] | ((uint_t)(d & (NPB - 1)) << 16);
    }
}

__global__ __launch_bounds__(256) void bucket_count_kernel(const uint_t* __restrict__ ebuf,
                                                           const int* __restrict__ hist,
                                                           int e, int K, int n,
                                                           int* __restrict__ cnt) {
    __shared__ int c64[NPB];
    int t = threadIdx.x, k = blockIdx.x;
    if (t < NPB) c64[t] = 0;
    __syncthreads();
    int lo = hist[k * PB];
    int hi = (k + 1 < K) ? hist[(k + 1) * PB] : e;
    for (int i = lo + t; i < hi; i += 256) atomicAdd(&c64[(ebuf[i] >> 16) & (NPB - 1)], 1);
    __syncthreads();
    int node = k * NPB + t;
    if (t < NPB && node < n) cnt[node] = c64[t];
}

// csr stored as ushort (requires n <= 65536)
__global__ __launch_bounds__(256) void bucket_fill_kernel(const uint_t* __restrict__ ebuf,
                                                          const int* __restrict__ hist,
                                                          const int* __restrict__ rowstart,
                                                          int e, int K, int n,
                                                          ushort_t* __restrict__ csr_src) {
    __shared__ int rs[NPB];
    __shared__ int c64[NPB];
    int t = threadIdx.x, k = blockIdx.x;
    if (t < NPB) {
        int node = k * NPB + t;
        rs[t] = (node < n) ? rowstart[node] : 0;
        c64[t] = 0;
    }
    __syncthreads();
    int lo = hist[k * PB];
    int hi = (k + 1 < K) ? hist[(k + 1) * PB] : e;
    for (int i = lo + t; i < hi; i += 256) {
        uint_t u = __builtin_nontemporal_load(ebuf + i);
        int dl = (u >> 16) & (NPB - 1);
        int slot = rs[dl] + atomicAdd(&c64[dl], 1);   // LDS atomic only
        csr_src[slot] = (ushort_t)(u & 0xffffu);
    }
}

// ---------- MFMA GEMM 128-col: g1_bf16 = dinv .* (x_fp32 @ W1) ----------
__global__ __launch_bounds__(256) void gemm128_mfma_kernel(const float* __restrict__ A,
                                                           const ushort_t* __restrict__ Wf,
                                                           const float* __restrict__ dinv,
                                                           ushort_t* __restrict__ out, int n) {
    __shared__ ushort_t Asl[64][136];   // +8 pad
    int t = threadIdx.x;
    int row0 = blockIdx.x * 64;

    #pragma unroll
    for (int it = 0; it < 4; ++it) {
        int idx = (it * 256 + t) * 8;
        int r = idx >> 7, k = idx & 127;
        int gr = row0 + r;
        uint4 p = {0u, 0u, 0u, 0u};
        if (gr < n) {
            float4 lo = *(const float4*)&A[(size_t)gr * 128 + k];
            float4 hi = *(const float4*)&A[(size_t)gr * 128 + k + 4];
            p.x = pack2bf(lo.x, lo.y); p.y = pack2bf(lo.z, lo.w);
            p.z = pack2bf(hi.x, hi.y); p.w = pack2bf(hi.z, hi.w);
        }
        *(uint4*)&Asl[r][k] = p;
    }
    __syncthreads();

    int wave = t >> 6, lane = t & 63;
    int rb = wave * 16;
    int lrow = rb + (lane & 15);
    int kg8 = (lane >> 4) * 8;

    bf16x8 a0 = *(const bf16x8*)&Asl[lrow][0 * 32 + kg8];
    bf16x8 a1 = *(const bf16x8*)&Asl[lrow][1 * 32 + kg8];
    bf16x8 a2 = *(const bf16x8*)&Asl[lrow][2 * 32 + kg8];
    bf16x8 a3 = *(const bf16x8*)&Asl[lrow][3 * 32 + kg8];

    f32x4 acc[8];
    #pragma unroll
    for (int ct = 0; ct < 8; ++ct) acc[ct] = (f32x4){0.f, 0.f, 0.f, 0.f};

    #pragma unroll
    for (int ct = 0; ct < 8; ++ct) {
        const bf16x8* Wp = (const bf16x8*)&Wf[(size_t)(ct * 4) * 64 * 8];
        bf16x8 b0 = Wp[0 * 64 + lane];
        bf16x8 b1 = Wp[1 * 64 + lane];
        bf16x8 b2 = Wp[2 * 64 + lane];
        bf16x8 b3 = Wp[3 * 64 + lane];
        acc[ct] = __builtin_amdgcn_mfma_f32_16x16x32_bf16(a0, b0, acc[ct], 0, 0, 0);
        acc[ct] = __builtin_amdgcn_mfma_f32_16x16x32_bf16(a1, b1, acc[ct], 0, 0, 0);
        acc[ct] = __builtin_amdgcn_mfma_f32_16x16x32_bf16(a2, b2, acc[ct], 0, 0, 0);
        acc[ct] = __builtin_amdgcn_mfma_f32_16x16x32_bf16(a3, b3, acc[ct], 0, 0, 0);
    }

    int orow0 = row0 + rb + (lane >> 4) * 4;
    int col0 = lane & 15;
    float dv[4];
    #pragma unroll
    for (int r = 0; r < 4; ++r) dv[r] = (orow0 + r < n) ? dinv[orow0 + r] : 0.f;
    #pragma unroll
    for (int ct = 0; ct < 8; ++ct) {
        #pragma unroll
        for (int r = 0; r < 4; ++r) {
            int row = orow0 + r;
            if (row < n) out[(size_t)row * 128 + ct * 16 + col0] = f2bf(acc[ct][r] * dv[r]);
        }
    }
}

// ---------- FUSED: aggregate128 (16 nodes/block, h2 -> LDS) + MFMA 16x64 -> g2 ----------
// Phase 1: wave w gathers nodes blk*16+w*4 .. +3 (proven agg128 mapping).
// Phase 2: wave w computes column tile ct=w of g2 via 4 MFMAs on W2f fragments.
__global__ __launch_bounds__(256) void fused_agg128_gemm64_mfma_kernel(
        const ushort_t* __restrict__ g,
        const int* __restrict__ rowstart,
        const ushort_t* __restrict__ csr_src,
        const float* __restrict__ dinv,
        const float* __restrict__ bias,      // b1
        const ushort_t* __restrict__ W2f,
        ushort_t* __restrict__ g2, int n) {
    __shared__ ushort_t h2sl[16][136];   // 4.3KB, +8 pad
    int t = threadIdx.x;
    int wave = t >> 6;
    int lane = t & 63;
    int eg = lane >> 3;        // edge sub-lane 0..7
    int f  = lane & 7;         // feature group: feats f*16..f*16+15 (32B)

    // ---- phase 1: 4 nodes per wave ----
    #pragma unroll
    for (int i = 0; i < 4; ++i) {
        int v = blockIdx.x * 16 + wave * 4 + i;
        if (v < n) {
            int s    = __builtin_amdgcn_readfirstlane(rowstart[v]);
            int epos = __builtin_amdgcn_readfirstlane(rowstart[v + 1]);

            float a0 = 0.f, a1 = 0.f, a2 = 0.f, a3 = 0.f, a4 = 0.f, a5 = 0.f, a6 = 0.f, a7 = 0.f;
            float a8 = 0.f, a9 = 0.f, aA = 0.f, aB = 0.f, aC = 0.f, aD = 0.f, aE = 0.f, aF = 0.f;
            if (lane < 8) {   // self row
                uint4 m0 = *(const uint4*)&g[(size_t)v * 128 + f * 16];
                uint4 m1 = *(const uint4*)&g[(size_t)v * 128 + f * 16 + 8];
                a0 = bf2f_lo(m0.x); a1 = bf2f_hi(m0.x);
                a2 = bf2f_lo(m0.y); a3 = bf2f_hi(m0.y);
                a4 = bf2f_lo(m0.z); a5 = bf2f_hi(m0.z);
                a6 = bf2f_lo(m0.w); a7 = bf2f_hi(m0.w);
                a8 = bf2f_lo(m1.x); a9 = bf2f_hi(m1.x);
                aA = bf2f_lo(m1.y); aB = bf2f_hi(m1.y);
                aC = bf2f_lo(m1.z); aD = bf2f_hi(m1.z);
                aE = bf2f_lo(m1.w); aF = bf2f_hi(m1.w);
            }

            #pragma unroll 2
            for (int j = s; j < epos; j += 8) {
                int idx = j + eg;
                int safe = min(idx, epos - 1);
                int u = csr_src[safe];
                float w = (idx < epos) ? 1.f : 0.f;
                uint4 m0 = *(const uint4*)&g[(size_t)u * 128 + f * 16];
                uint4 m1 = *(const uint4*)&g[(size_t)u * 128 + f * 16 + 8];
                a0 = fmaf(w, bf2f_lo(m0.x), a0); a1 = fmaf(w, bf2f_hi(m0.x), a1);
                a2 = fmaf(w, bf2f_lo(m0.y), a2); a3 = fmaf(w, bf2f_hi(m0.y), a3);
                a4 = fmaf(w, bf2f_lo(m0.z), a4); a5 = fmaf(w, bf2f_hi(m0.z), a5);
                a6 = fmaf(w, bf2f_lo(m0.w), a6); a7 = fmaf(w, bf2f_hi(m0.w), a7);
                a8 = fmaf(w, bf2f_lo(m1.x), a8); a9 = fmaf(w, bf2f_hi(m1.x), a9);
                aA = fmaf(w, bf2f_lo(m1.y), aA); aB = fmaf(w, bf2f_hi(m1.y), aB);
                aC = fmaf(w, bf2f_lo(m1.z), aC); aD = fmaf(w, bf2f_hi(m1.z), aD);
                aE = fmaf(w, bf2f_lo(m1.w), aE); aF = fmaf(w, bf2f_hi(m1.w), aF);
            }

            #pragma unroll
            for (int m = 8; m <= 32; m <<= 1) {
                a0 += __shfl_xor(a0, m); a1 += __shfl_xor(a1, m);
                a2 += __shfl_xor(a2, m); a3 += __shfl_xor(a3, m);
                a4 += __shfl_xor(a4, m); a5 += __shfl_xor(a5, m);
                a6 += __shfl_xor(a6, m); a7 += __shfl_xor(a7, m);
                a8 += __shfl_xor(a8, m); a9 += __shfl_xor(a9, m);
                aA += __shfl_xor(aA, m); aB += __shfl_xor(aB, m);
                aC += __shfl_xor(aC, m); aD += __shfl_xor(aD, m);
                aE += __shfl_xor(aE, m); aF += __shfl_xor(aF, m);
            }

            if (lane < 8) {
                float dv = dinv[v];
                int c0 = f * 16;
                float4 b0 = *(const float4*)&bias[c0];
                float4 b1 = *(const float4*)&bias[c0 + 4];
                float4 b2 = *(const float4*)&bias[c0 + 8];
                float4 b3 = *(const float4*)&bias[c0 + 12];
                float o00 = fmaxf(fmaf(a0, dv, b0.x), 0.f), o01 = fmaxf(fmaf(a1, dv, b0.y), 0.f);
                float o02 = fmaxf(fmaf(a2, dv, b0.z), 0.f), o03 = fmaxf(fmaf(a3, dv, b0.w), 0.f);
                float o04 = fmaxf(fmaf(a4, dv, b1.x), 0.f), o05 = fmaxf(fmaf(a5, dv, b1.y), 0.f);
                float o06 = fmaxf(fmaf(a6, dv, b1.z), 0.f), o07 = fmaxf(fmaf(a7, dv, b1.w), 0.f);
                float o08 = fmaxf(fmaf(a8, dv, b2.x), 0.f), o09 = fmaxf(fmaf(a9, dv, b2.y), 0.f);
                float o10 = fmaxf(fmaf(aA, dv, b2.z), 0.f), o11 = fmaxf(fmaf(aB, dv, b2.w), 0.f);
                float o12 = fmaxf(fmaf(aC, dv, b3.x), 0.f), o13 = fmaxf(fmaf(aD, dv, b3.y), 0.f);
                float o14 = fmaxf(fmaf(aE, dv, b3.z), 0.f), o15 = fmaxf(fmaf(aF, dv, b3.w), 0.f);
                uint4 p0 = {pack2bf(o00, o01), pack2bf(o02, o03),
                            pack2bf(o04, o05), pack2bf(o06, o07)};
                uint4 p1 = {pack2bf(o08, o09), pack2bf(o10, o11),
                            pack2bf(o12, o13), pack2bf(o14, o15)};
                int nd = wave * 4 + i;
                *(uint4*)&h2sl[nd][c0]     = p0;
                *(uint4*)&h2sl[nd][c0 + 8] = p1;
            }
        }
    }
    __syncthreads();

    // ---- phase 2: wave = one 16-col tile (ct = wave), rows = 16 block nodes ----
    int lrow = lane & 15;
    int kg8 = (lane >> 4) * 8;
    bf16x8 a0 = *(const bf16x8*)&h2sl[lrow][0 * 32 + kg8];
    bf16x8 a1 = *(const bf16x8*)&h2sl[lrow][1 * 32 + kg8];
    bf16x8 a2 = *(const bf16x8*)&h2sl[lrow][2 * 32 + kg8];
    bf16x8 a3 = *(const bf16x8*)&h2sl[lrow][3 * 32 + kg8];

    f32x4 acc = (f32x4){0.f, 0.f, 0.f, 0.f};
    const bf16x8* Wp = (const bf16x8*)&W2f[(size_t)(wave * 4) * 64 * 8];
    acc = __builtin_amdgcn_mfma_f32_16x16x32_bf16(a0, Wp[0 * 64 + lane], acc, 0, 0, 0);
    acc = __builtin_amdgcn_mfma_f32_16x16x32_bf16(a1, Wp[1 * 64 + lane], acc, 0, 0, 0);
    acc = __builtin_amdgcn_mfma_f32_16x16x32_bf16(a2, Wp[2 * 64 + lane], acc, 0, 0, 0);
    acc = __builtin_amdgcn_mfma_f32_16x16x32_bf16(a3, Wp[3 * 64 + lane], acc, 0, 0, 0);

    int orow0 = blockIdx.x * 16 + (lane >> 4) * 4;
    int col = wave * 16 + (lane & 15);
    #pragma unroll
    for (int r = 0; r < 4; ++r) {
        int row = orow0 + r;
        if (row < n) g2[(size_t)row * 64 + col] = f2bf(acc[r] * dinv[row]);
    }
}

// ---------- aggregation 64-col (final layer) ----------
__global__ __launch_bounds__(256) void aggregate64_kernel(const ushort_t* __restrict__ g,
                                                          const int* __restrict__ rowstart,
                                                          const ushort_t* __restrict__ csr_src,
                                                          const float* __restrict__ dinv,
                                                          const float* __restrict__ bias,
                                                          float* __restrict__ out, int n) {
    int wave = threadIdx.x >> 6;
    int lane = threadIdx.x & 63;
    int v = blockIdx.x * 4 + wave;
    if (v >= n) return;
    int s    = __builtin_amdgcn_readfirstlane(rowstart[v]);
    int epos = __builtin_amdgcn_readfirstlane(rowstart[v + 1]);
    int eg = lane >> 3;        // edge sub-lane 0..7
    int f  = lane & 7;         // feats f*8..f*8+7

    float a0 = 0.f, a1 = 0.f, a2 = 0.f, a3 = 0.f, a4 = 0.f, a5 = 0.f, a6 = 0.f, a7 = 0.f;
    if (lane < 8) {   // self row
        uint4 m = *(const uint4*)&g[(size_t)v * 64 + f * 8];
        a0 = bf2f_lo(m.x); a1 = bf2f_hi(m.x);
        a2 = bf2f_lo(m.y); a3 = bf2f_hi(m.y);
        a4 = bf2f_lo(m.z); a5 = bf2f_hi(m.z);
        a6 = bf2f_lo(m.w); a7 = bf2f_hi(m.w);
    }

    #pragma unroll 2
    for (int j = s; j < epos; j += 8) {
        int idx = j + eg;
        int safe = min(idx, epos - 1);
        int u = __builtin_nontemporal_load(csr_src + safe);
        float w = (idx < epos) ? 1.f : 0.f;
        uint4 m = *(const uint4*)&g[(size_t)u * 64 + f * 8];
        a0 = fmaf(w, bf2f_lo(m.x), a0); a1 = fmaf(w, bf2f_hi(m.x), a1);
        a2 = fmaf(w, bf2f_lo(m.y), a2); a3 = fmaf(w, bf2f_hi(m.y), a3);
        a4 = fmaf(w, bf2f_lo(m.z), a4); a5 = fmaf(w, bf2f_hi(m.z), a5);
        a6 = fmaf(w, bf2f_lo(m.w), a6); a7 = fmaf(w, bf2f_hi(m.w), a7);
    }

    a0 += __shfl_xor(a0, 8);  a1 += __shfl_xor(a1, 8);
    a2 += __shfl_xor(a2, 8);  a3 += __shfl_xor(a3, 8);
    a4 += __shfl_xor(a4, 8);  a5 += __shfl_xor(a5, 8);
    a6 += __shfl_xor(a6, 8);  a7 += __shfl_xor(a7, 8);
    a0 += __shfl_xor(a0, 16); a1 += __shfl_xor(a1, 16);
    a2 += __shfl_xor(a2, 16); a3 += __shfl_xor(a3, 16);
    a4 += __shfl_xor(a4, 16); a5 += __shfl_xor(a5, 16);
    a6 += __shfl_xor(a6, 16); a7 += __shfl_xor(a7, 16);
    a0 += __shfl_xor(a0, 32); a1 += __shfl_xor(a1, 32);
    a2 += __shfl_xor(a2, 32); a3 += __shfl_xor(a3, 32);
    a4 += __shfl_xor(a4, 32); a5 += __shfl_xor(a5, 32);
    a6 += __shfl_xor(a6, 32); a7 += __shfl_xor(a7, 32);

    if (lane < 8) {
        float dv = dinv[v];
        float4 b0 = *(const float4*)&bias[f * 8];
        float4 b1 = *(const float4*)&bias[f * 8 + 4];
        float4 o0 = {fmaxf(fmaf(a0, dv, b0.x), 0.f), fmaxf(fmaf(a1, dv, b0.y), 0.f),
                     fmaxf(fmaf(a2, dv, b0.z), 0.f), fmaxf(fmaf(a3, dv, b0.w), 0.f)};
        float4 o1 = {fmaxf(fmaf(a4, dv, b1.x), 0.f), fmaxf(fmaf(a5, dv, b1.y), 0.f),
                     fmaxf(fmaf(a6, dv, b1.z), 0.f), fmaxf(fmaf(a7, dv, b1.w), 0.f)};
        *(float4*)&out[(size_t)v * 64 + f * 8] = o0;
        *(float4*)&out[(size_t)v * 64 + f * 8 + 4] = o1;
    }
}

extern "C" void kernel_launch(void* const* d_in, const int* in_sizes, int n_in,
                              void* d_out, int out_size, void* d_ws, size_t ws_size,
                              hipStream_t stream) {
    const float* x  = (const float*)d_in[0];
    const int*   ei = (const int*)d_in[1];   // [2, E] int32
    const float* W1 = (const float*)d_in[2];
    const float* b1 = (const float*)d_in[3];
    const float* W2 = (const float*)d_in[4];
    const float* b2 = (const float*)d_in[5];
    float* out = (float*)d_out;

    const int n = in_sizes[0] / 128;   // 50000 (<= 65536 required for packing)
    const int e = in_sizes[1] / 2;     // 800000
    const int* src = ei;
    const int* dst = ei + e;
    const int K   = (n + NPB - 1) / NPB;       // 782 buckets
    const int epb = (e + PB - 1) / PB;         // edges per chunk-block
    const int L   = K * PB;                    // flat histogram length

    char* ws = (char*)d_ws;
    size_t off = 0;
    auto carve = [&](size_t bytes) -> void* {
        void* p = ws + off;
        off = (off + bytes + 255) & ~(size_t)255;
        return p;
    };
    int*      hist     = (int*)     carve((size_t)L * 4);
    int*      bsum     = (int*)     carve((size_t)1024 * 4);
    int*      cnt      = (int*)     carve((size_t)n * 4);
    int*      rowstart = (int*)     carve((size_t)(n + 1) * 4);
    float*    dinv     = (float*)   carve((size_t)n * 4);
    uint_t*   ebuf     = (uint_t*)  carve((size_t)e * 4);
    ushort_t* csr_src  = (ushort_t*)carve((size_t)e * 2);
    ushort_t* W1f      = (ushort_t*)carve((size_t)128 * 128 * 2);
    ushort_t* W2f      = (ushort_t*)carve((size_t)128 * 64 * 2);
    ushort_t* g1       = (ushort_t*)carve((size_t)n * 128 * 2);
    ushort_t* g2       = (ushort_t*)carve((size_t)n * 64 * 2);
    (void)ws_size;

    const int nbL = (L + 1023) / 1024;   // hist scan blocks (196 <= 256 OK)
    const int nbN = (n + 1023) / 1024;   // node scan blocks (49)

    // --- CSR build + W prep (zero global atomics, zero memsets), 6 launches ---
    bucket_hist_kernel<<<PB, 256, 0, stream>>>(dst, e, epb, K, hist, W1, W2, W1f, W2f);
    block_sum_kernel<<<nbL, 256, 0, stream>>>(hist, L, bsum);
    local_scan_apply_kernel<<<nbL, 256, 0, stream>>>(hist, L, bsum, nbL);
    partition_kernel<<<PB, 256, 0, stream>>>(src, dst, e, epb, K, hist, ebuf);
    bucket_count_kernel<<<K, 256, 0, stream>>>(ebuf, hist, e, K, n, cnt);
    local_scan_node_kernel<<<nbN, 256, 0, stream>>>(cnt, n, hist, e, rowstart, dinv);
    bucket_fill_kernel<<<K, 256, 0, stream>>>(ebuf, hist, rowstart, e, K, n, csr_src);

    // --- layers (h2 never touches HBM), 3 launches ---
    const int gblocks = (n + 63) / 64;
    const int fblocks = (n + 15) / 16;
    const int ablocks = (n + 3) / 4;
    gemm128_mfma_kernel<<<gblocks, 256, 0, stream>>>(x, W1f, dinv, g1, n);
    fused_agg128_gemm64_mfma_kernel<<<fblocks, 256, 0, stream>>>(g1, rowstart, csr_src,
                                                                 dinv, b1, W2f, g2, n);
    aggregate64_kernel<<<ablocks, 256, 0, stream>>>(g2, rowstart, csr_src, dinv, b2, out, n);
}